// Round 1
// baseline (678.374 us; speedup 1.0000x reference)
//
#include <hip/hip_runtime.h>
#include <math.h>

#define INV_SQRT2F 0.70710678118654752440f

// ---------------- compile-time algebra tables ----------------
struct Tables {
  int   kof[8][8];    // kof[j][i] = k s.t. blade_i * blade_k = +/- blade_j
  float cs[8][8];     // sign of that pair
  int   widx[8][8];   // grade-triple index gi*16+gj*4+gk
  float csf[64];      // sign for flat pair ik = i*8+k
};
constexpr int t_bm(int i){ constexpr int t[8] = {0,1,2,4,3,5,6,7}; return t[i]; }
constexpr int t_idx(int b){ constexpr int t[8] = {0,1,2,4,3,5,6,7}; return t[b]; } // involution
constexpr int t_gr(int i){ constexpr int t[8] = {0,1,1,1,2,2,2,3}; return t[i]; }
constexpr int t_pc(int x){ int c=0; while(x){ c += x&1; x >>= 1; } return c; }
constexpr float t_sign(int a, int b){
  float s = 1.f; int aa = a >> 1;
  while(aa){ if(t_pc(aa & b) & 1) s = -s; aa >>= 1; }
  return s;
}
constexpr Tables mkTables(){
  Tables T{};
  for(int i=0;i<8;i++) for(int k=0;k<8;k++) T.csf[i*8+k] = t_sign(t_bm(i), t_bm(k));
  for(int j=0;j<8;j++) for(int i=0;i<8;i++){
    int k = t_idx(t_bm(i) ^ t_bm(j));
    T.kof[j][i]  = k;
    T.cs[j][i]   = t_sign(t_bm(i), t_bm(k));
    T.widx[j][i] = t_gr(i)*16 + t_gr(j)*4 + t_gr(k);
  }
  return T;
}
__device__ const Tables d_TB = mkTables();

__device__ __forceinline__ float sigf(float z){ return 1.f / (1.f + __expf(-z)); }
__device__ __forceinline__ int gradeOfIdx(int i){ return (i==0)?0:((i<4)?1:((i<7)?2:3)); }

// ---------------- K1: lin_r1[b,n,i] = sum_m x[b,m,i] * w_right1[n,m,g(i)] ----------------
#define K1_BM 128
#define K1_BN 128
#define K1_BK 16
__global__ __launch_bounds__(256) void k1_linr(const float* __restrict__ x,
                                               const float* __restrict__ w,
                                               float* __restrict__ y){
  __shared__ __align__(16) float As[K1_BK][K1_BM+4];
  __shared__ __align__(16) float Ws[K1_BK][K1_BN+4];
  const int tid = threadIdx.x;
  const int b0 = blockIdx.x * K1_BM;
  const int n0 = blockIdx.y * K1_BN;
  const int i  = blockIdx.z;
  const int g  = gradeOfIdx(i);
  const int tx = tid & 15, ty = tid >> 4;

  float acc[8][8];
  #pragma unroll
  for(int p=0;p<8;p++){
    #pragma unroll
    for(int q=0;q<8;q++) acc[p][q] = 0.f;
  }

  for(int mk = 0; mk < 512; mk += K1_BK){
    #pragma unroll
    for(int r=0;r<8;r++){
      int s = tid + r*256;
      int mm = s & 15, bb = s >> 4;
      As[mm][bb] = x[((size_t)(b0+bb)*512 + (mk+mm))*8 + i];
      Ws[mm][bb] = w[((size_t)(n0+bb)*512 + (mk+mm))*4 + g];
    }
    __syncthreads();
    #pragma unroll
    for(int mm=0; mm<K1_BK; mm++){
      float a[8], bv[8];
      *(float4*)&a[0]  = *(const float4*)&As[mm][ty*8];
      *(float4*)&a[4]  = *(const float4*)&As[mm][ty*8+4];
      *(float4*)&bv[0] = *(const float4*)&Ws[mm][tx*8];
      *(float4*)&bv[4] = *(const float4*)&Ws[mm][tx*8+4];
      #pragma unroll
      for(int p=0;p<8;p++){
        #pragma unroll
        for(int q=0;q<8;q++) acc[p][q] = fmaf(a[p], bv[q], acc[p][q]);
      }
    }
    __syncthreads();
  }
  #pragma unroll
  for(int p=0;p<8;p++){
    size_t b = b0 + ty*8 + p;
    #pragma unroll
    for(int q=0;q<8;q++){
      size_t n = n0 + tx*8 + q;
      y[(b*512 + n)*8 + i] = acc[p][q];
    }
  }
}

// ---------------- K2: fcgp1 prod + left (partial over n-split) ----------------
#define K2_BT 32
#define K2_NS 4
__global__ __launch_bounds__(256) void k2_prod(const float* __restrict__ x,
                                               const float* __restrict__ linr,
                                               const float* __restrict__ norm_a,
                                               const float* __restrict__ gpw,
                                               const float* __restrict__ wl,
                                               float* __restrict__ h1part){
  __shared__ __align__(16) float xv[8][36];   // [i][b]
  __shared__ __align__(16) float xr[8][36];   // [k][b]  (normalized)
  __shared__ __align__(16) float tt[64][36];  // [ik][b] signed pair products
  __shared__ __align__(16) float ws[64][36];  // [triple][m]
  __shared__ __align__(16) float wlt[4][36];  // [g][m]
  const int tid = threadIdx.x;
  const int j  = tid >> 5;
  const int mg = (tid >> 2) & 7;
  const int br = tid & 3;
  const int b0 = blockIdx.x * K2_BT;
  const int n_beg = blockIdx.y * (512 / K2_NS);
  const int n_end = n_beg + (512 / K2_NS);

  int tti[8], wix[8];
  #pragma unroll
  for(int p=0;p<8;p++){
    int k = d_TB.kof[j][p];
    tti[p] = p*8 + k;
    wix[p] = d_TB.widx[j][p];
  }
  const int gj = gradeOfIdx(j);
  const int ikc = tid >> 2;
  const int bqc = (tid & 3) * 8;
  const float csfv = d_TB.csf[ikc];
  const int ic = ikc >> 3, kc = ikc & 7;

  float acc[4][8];
  #pragma unroll
  for(int mi=0;mi<4;mi++){
    #pragma unroll
    for(int b=0;b<8;b++) acc[mi][b] = 0.f;
  }

  for(int n = n_beg; n < n_end; n++){
    // ---- stage ----
    {
      int q0 = tid*2;
      #pragma unroll
      for(int r=0;r<2;r++){
        int q = q0 + r;
        int m = q >> 4, seg = q & 15;
        float4 v = *(const float4*)&gpw[((size_t)m*512 + n)*64 + seg*4];
        ws[seg*4+0][m] = v.x; ws[seg*4+1][m] = v.y;
        ws[seg*4+2][m] = v.z; ws[seg*4+3][m] = v.w;
      }
      if(tid < 32){
        int b = tid;
        const float* px = &x[((size_t)(b0+b)*512 + n)*8];
        float4 u0 = *(const float4*)px, u1 = *(const float4*)(px+4);
        xv[0][b]=u0.x; xv[1][b]=u0.y; xv[2][b]=u0.z; xv[3][b]=u0.w;
        xv[4][b]=u1.x; xv[5][b]=u1.y; xv[6][b]=u1.z; xv[7][b]=u1.w;
      } else if(tid < 64){
        int b = tid - 32;
        const float* pr = &linr[((size_t)(b0+b)*512 + n)*8];
        float4 u0 = *(const float4*)pr, u1 = *(const float4*)(pr+4);
        float4 na = *(const float4*)&norm_a[n*4];
        float s0 = sigf(na.x)*(fabsf(u0.x)-1.f)+1.f+1e-6f;
        float s1 = sigf(na.y)*(sqrtf(u0.y*u0.y+u0.z*u0.z+u0.w*u0.w)-1.f)+1.f+1e-6f;
        float s2 = sigf(na.z)*(sqrtf(u1.x*u1.x+u1.y*u1.y+u1.z*u1.z)-1.f)+1.f+1e-6f;
        float s3 = sigf(na.w)*(fabsf(u1.w)-1.f)+1.f+1e-6f;
        xr[0][b]=u0.x/s0; xr[1][b]=u0.y/s1; xr[2][b]=u0.z/s1; xr[3][b]=u0.w/s1;
        xr[4][b]=u1.x/s2; xr[5][b]=u1.y/s2; xr[6][b]=u1.z/s2; xr[7][b]=u1.w/s3;
      } else if(tid < 96){
        int m = tid - 64;
        float4 v = *(const float4*)&wl[((size_t)m*512 + n)*4];
        wlt[0][m]=v.x; wlt[1][m]=v.y; wlt[2][m]=v.z; wlt[3][m]=v.w;
      }
    }
    __syncthreads();
    // ---- signed pair products ----
    {
      float4 a0 = *(const float4*)&xv[ic][bqc];
      float4 a1 = *(const float4*)&xv[ic][bqc+4];
      float4 c0 = *(const float4*)&xr[kc][bqc];
      float4 c1 = *(const float4*)&xr[kc][bqc+4];
      float4 t0, t1;
      t0.x = csfv*a0.x*c0.x; t0.y = csfv*a0.y*c0.y;
      t0.z = csfv*a0.z*c0.z; t0.w = csfv*a0.w*c0.w;
      t1.x = csfv*a1.x*c1.x; t1.y = csfv*a1.y*c1.y;
      t1.z = csfv*a1.z*c1.z; t1.w = csfv*a1.w*c1.w;
      *(float4*)&tt[ikc][bqc]   = t0;
      *(float4*)&tt[ikc][bqc+4] = t1;
    }
    __syncthreads();
    // ---- accumulate ----
    #pragma unroll
    for(int p=0;p<8;p++){
      float4 w4 = *(const float4*)&ws[wix[p]][mg*4];
      float4 t0 = *(const float4*)&tt[tti[p]][br*8];
      float4 t1 = *(const float4*)&tt[tti[p]][br*8+4];
      float tb[8] = {t0.x,t0.y,t0.z,t0.w,t1.x,t1.y,t1.z,t1.w};
      float wm[4] = {w4.x,w4.y,w4.z,w4.w};
      #pragma unroll
      for(int mi=0;mi<4;mi++){
        #pragma unroll
        for(int b=0;b<8;b++) acc[mi][b] = fmaf(wm[mi], tb[b], acc[mi][b]);
      }
    }
    { // left term
      float4 w4 = *(const float4*)&wlt[gj][mg*4];
      float4 x0 = *(const float4*)&xv[j][br*8];
      float4 x1 = *(const float4*)&xv[j][br*8+4];
      float xb[8] = {x0.x,x0.y,x0.z,x0.w,x1.x,x1.y,x1.z,x1.w};
      float wm[4] = {w4.x,w4.y,w4.z,w4.w};
      #pragma unroll
      for(int mi=0;mi<4;mi++){
        #pragma unroll
        for(int b=0;b<8;b++) acc[mi][b] = fmaf(wm[mi], xb[b], acc[mi][b]);
      }
    }
    __syncthreads();
  }
  float* outp = h1part + (size_t)blockIdx.y * (4096u*32u*8u);
  #pragma unroll
  for(int mi=0;mi<4;mi++){
    int m = mg*4 + mi;
    #pragma unroll
    for(int b=0;b<8;b++){
      size_t bb = b0 + br*8 + b;
      outp[(bb*32 + m)*8 + j] = acc[mi][b];
    }
  }
}

// ---------------- K2b: reduce splits + bias + scale + silu -> h1s ----------------
__global__ __launch_bounds__(256) void k2b_silu(const float* __restrict__ h1part,
                                                const float* __restrict__ bl,
                                                const float* __restrict__ sa,
                                                const float* __restrict__ sb,
                                                float* __restrict__ h1s){
  int idx = blockIdx.x*256 + threadIdx.x;  // (b,m)
  int m = idx & 31;
  float v[8];
  #pragma unroll
  for(int h=0;h<2;h++){
    float sx=0.f, sy=0.f, sz=0.f, sw=0.f;
    #pragma unroll
    for(int sp=0; sp<K2_NS; sp++){
      float4 u = *(const float4*)&h1part[(size_t)sp*(4096u*32u*8u) + (size_t)idx*8 + h*4];
      sx+=u.x; sy+=u.y; sz+=u.z; sw+=u.w;
    }
    v[h*4+0]=sx; v[h*4+1]=sy; v[h*4+2]=sz; v[h*4+3]=sw;
  }
  v[0] += bl[m];
  #pragma unroll
  for(int i=0;i<8;i++) v[i] *= INV_SQRT2F;
  float q1 = v[1]*v[1]+v[2]*v[2]+v[3]*v[3];
  float q2 = v[4]*v[4]+v[5]*v[5]+v[6]*v[6];
  float q3 = v[7]*v[7];
  float4 sa4 = *(const float4*)&sa[m*4];
  float4 sb4 = *(const float4*)&sb[m*4];
  float g0 = sigf(sa4.x*v[0] + sb4.x);
  float g1 = sigf(sa4.y*q1   + sb4.y);
  float g2 = sigf(sa4.z*q2   + sb4.z);
  float g3 = sigf(sa4.w*q3   + sb4.w);
  float4 o0 = make_float4(g0*v[0], g1*v[1], g1*v[2], g1*v[3]);
  float4 o1 = make_float4(g2*v[4], g2*v[5], g2*v[6], g3*v[7]);
  *(float4*)&h1s[(size_t)idx*8]     = o0;
  *(float4*)&h1s[(size_t)idx*8 + 4] = o1;
}

// ---------------- K3: sgp + silu + fcgp3 -> out ----------------
__device__ __forceinline__ void linrow32(const float (*src)[32][8], int b, int n,
                                         const float* __restrict__ wr, float* lin){
  for(int m=0;m<32;m++){
    float4 w  = *(const float4*)&wr[(n*32+m)*4];
    float4 h0 = *(const float4*)&src[b][m][0];
    float4 h1 = *(const float4*)&src[b][m][4];
    lin[0] = fmaf(h0.x, w.x, lin[0]);
    lin[1] = fmaf(h0.y, w.y, lin[1]);
    lin[2] = fmaf(h0.z, w.y, lin[2]);
    lin[3] = fmaf(h0.w, w.y, lin[3]);
    lin[4] = fmaf(h1.x, w.z, lin[4]);
    lin[5] = fmaf(h1.y, w.z, lin[5]);
    lin[6] = fmaf(h1.z, w.z, lin[6]);
    lin[7] = fmaf(h1.w, w.w, lin[7]);
  }
}
__device__ __forceinline__ void norm8(float* v, float4 na){
  float s0 = sigf(na.x)*(fabsf(v[0])-1.f)+1.f+1e-6f;
  float s1 = sigf(na.y)*(sqrtf(v[1]*v[1]+v[2]*v[2]+v[3]*v[3])-1.f)+1.f+1e-6f;
  float s2 = sigf(na.z)*(sqrtf(v[4]*v[4]+v[5]*v[5]+v[6]*v[6])-1.f)+1.f+1e-6f;
  float s3 = sigf(na.w)*(fabsf(v[7])-1.f)+1.f+1e-6f;
  v[0]/=s0; v[1]/=s1; v[2]/=s1; v[3]/=s1; v[4]/=s2; v[5]/=s2; v[6]/=s2; v[7]/=s3;
}

__global__ __launch_bounds__(256) void k3_tail(const float* __restrict__ h1s,
    const float* __restrict__ w2r, const float* __restrict__ na2,
    const float* __restrict__ w2l, const float* __restrict__ b2l,
    const float* __restrict__ gw2,
    const float* __restrict__ sa, const float* __restrict__ sb,
    const float* __restrict__ w3r, const float* __restrict__ na3,
    const float* __restrict__ w3l, const float* __restrict__ b3l,
    const float* __restrict__ gw3,
    float* __restrict__ out){
  __shared__ __align__(16) float hs[8][32][8];
  __shared__ __align__(16) float x2[8][32][8];
  __shared__ __align__(16) float h2[8][32][8];
  __shared__ __align__(16) float x3[8][32][8];
  __shared__ __align__(16) float gw2s[32][65];
  const int tid = threadIdx.x;
  const int b0 = blockIdx.x * 8;
  {
    const float4* src = (const float4*)(h1s + (size_t)b0*256);
    float4* dst = (float4*)&hs[0][0][0];
    dst[tid] = src[tid]; dst[tid+256] = src[tid+256];
    const float4* g2 = (const float4*)gw2;
    #pragma unroll
    for(int r=0;r<2;r++){
      float4 v = g2[tid + r*256];
      int flat = (tid + r*256)*4;
      int n = flat >> 6, w = flat & 63;
      gw2s[n][w]=v.x; gw2s[n][w+1]=v.y; gw2s[n][w+2]=v.z; gw2s[n][w+3]=v.w;
    }
  }
  __syncthreads();
  const int b = tid >> 5, n = tid & 31;
  // phase B: lin_r2 + norm -> x2
  {
    float lin[8] = {0,0,0,0,0,0,0,0};
    linrow32(hs, b, n, w2r, lin);
    norm8(lin, *(const float4*)&na2[n*4]);
    *(float4*)&x2[b][n][0] = make_float4(lin[0],lin[1],lin[2],lin[3]);
    *(float4*)&x2[b][n][4] = make_float4(lin[4],lin[5],lin[6],lin[7]);
  }
  __syncthreads();
  // phase C: sgp prod + left + bias + scale + silu -> h2
  {
    float pr[8] = {0,0,0,0,0,0,0,0};
    #pragma unroll
    for(int j=0;j<8;j++){
      #pragma unroll
      for(int i=0;i<8;i++){
        const int k = t_idx(t_bm(i)^t_bm(j));
        const float sgn = t_sign(t_bm(i), t_bm(k));
        const int wix = t_gr(i)*16 + t_gr(j)*4 + t_gr(k);
        pr[j] = fmaf(sgn * hs[b][n][i] * x2[b][n][k], gw2s[n][wix], pr[j]);
      }
    }
    float lf[8] = {0,0,0,0,0,0,0,0};
    linrow32(hs, b, n, w2l, lf);
    float v[8];
    #pragma unroll
    for(int j=0;j<8;j++) v[j] = (pr[j] + lf[j] + ((j==0) ? b2l[n] : 0.f)) * INV_SQRT2F;
    float q1 = v[1]*v[1]+v[2]*v[2]+v[3]*v[3];
    float q2 = v[4]*v[4]+v[5]*v[5]+v[6]*v[6];
    float q3 = v[7]*v[7];
    float4 sa4 = *(const float4*)&sa[n*4];
    float4 sb4 = *(const float4*)&sb[n*4];
    float g0 = sigf(sa4.x*v[0] + sb4.x);
    float g1 = sigf(sa4.y*q1   + sb4.y);
    float g2 = sigf(sa4.z*q2   + sb4.z);
    float g3 = sigf(sa4.w*q3   + sb4.w);
    *(float4*)&h2[b][n][0] = make_float4(g0*v[0], g1*v[1], g1*v[2], g1*v[3]);
    *(float4*)&h2[b][n][4] = make_float4(g2*v[4], g2*v[5], g2*v[6], g3*v[7]);
  }
  __syncthreads();
  // phase D: lin_r3 + norm -> x3
  {
    float lin[8] = {0,0,0,0,0,0,0,0};
    linrow32(h2, b, n, w3r, lin);
    norm8(lin, *(const float4*)&na3[n*4]);
    *(float4*)&x3[b][n][0] = make_float4(lin[0],lin[1],lin[2],lin[3]);
    *(float4*)&x3[b][n][4] = make_float4(lin[4],lin[5],lin[6],lin[7]);
  }
  __syncthreads();
  // phase E: fcgp3 prod + left -> out  (576 outputs per block)
  for(int to = tid; to < 576; to += 256){
    int bb = to / 72;
    int r  = to - bb*72;
    int mo = r >> 3, j = r & 7;
    int kof_r[8], wix_r[8]; float cs_r[8];
    #pragma unroll
    for(int i=0;i<8;i++){
      kof_r[i] = d_TB.kof[j][i];
      cs_r[i]  = d_TB.cs[j][i];
      wix_r[i] = d_TB.widx[j][i];
    }
    const int gj = gradeOfIdx(j);
    float acc = 0.f, accL = 0.f;
    for(int nn=0; nn<32; nn++){
      const float* gp  = &gw3[((size_t)mo*32+nn)*64];
      const float* hh  = &h2[bb][nn][0];
      const float* xrr = &x3[bb][nn][0];
      #pragma unroll
      for(int i=0;i<8;i++)
        acc = fmaf(cs_r[i]*hh[i], xrr[kof_r[i]] * gp[wix_r[i]], acc);
      accL = fmaf(hh[j], w3l[((size_t)mo*32+nn)*4 + gj], accL);
    }
    float res = (acc + accL + ((j==0) ? b3l[mo] : 0.f)) * INV_SQRT2F;
    out[((size_t)(b0+bb)*9 + mo)*8 + j] = res;
  }
}

// ---------------- launch ----------------
extern "C" void kernel_launch(void* const* d_in, const int* in_sizes, int n_in,
                              void* d_out, int out_size, void* d_ws, size_t ws_size,
                              hipStream_t stream){
  const float* x        = (const float*)d_in[0];
  const float* w_right1 = (const float*)d_in[1];
  const float* norm_a1  = (const float*)d_in[2];
  const float* w_left1  = (const float*)d_in[3];
  const float* b_left1  = (const float*)d_in[4];
  const float* gp_w1    = (const float*)d_in[5];
  const float* silu_a   = (const float*)d_in[6];
  const float* silu_b   = (const float*)d_in[7];
  const float* w_right2 = (const float*)d_in[8];
  const float* norm_a2  = (const float*)d_in[9];
  const float* w_left2  = (const float*)d_in[10];
  const float* b_left2  = (const float*)d_in[11];
  const float* gp_w2    = (const float*)d_in[12];
  const float* w_right3 = (const float*)d_in[13];
  const float* norm_a3  = (const float*)d_in[14];
  const float* w_left3  = (const float*)d_in[15];
  const float* b_left3  = (const float*)d_in[16];
  const float* gp_w3    = (const float*)d_in[17];
  float* out = (float*)d_out;

  float* linr1  = (float*)d_ws;                          // 4096*512*8
  float* h1part = linr1 + (size_t)4096*512*8;            // 4 * 4096*32*8
  float* h1s    = h1part + (size_t)K2_NS*4096*32*8;      // 4096*32*8

  k1_linr<<<dim3(32, 4, 8), 256, 0, stream>>>(x, w_right1, linr1);
  k2_prod<<<dim3(4096/K2_BT, K2_NS), 256, 0, stream>>>(x, linr1, norm_a1, gp_w1, w_left1, h1part);
  k2b_silu<<<dim3(4096*32/256), 256, 0, stream>>>(h1part, b_left1, silu_a, silu_b, h1s);
  k3_tail<<<dim3(4096/8), 256, 0, stream>>>(h1s,
      w_right2, norm_a2, w_left2, b_left2, gp_w2,
      silu_a, silu_b,
      w_right3, norm_a3, w_left3, b_left3, gp_w3,
      out);
}

// Round 2
// 467.861 us; speedup vs baseline: 1.4499x; 1.4499x over previous
//
#include <hip/hip_runtime.h>
#include <hip/hip_bf16.h>
#include <math.h>

#define INV_SQRT2F 0.70710678118654752440f
#define AS1 __attribute__((address_space(1)))
#define AS3 __attribute__((address_space(3)))

typedef __attribute__((ext_vector_type(8))) short short8;
typedef __attribute__((ext_vector_type(4))) float floatx4;

// ---------------- compile-time algebra tables ----------------
struct Tables {
  int   kof[8][8];    // kof[j][i] = k s.t. blade_i * blade_k = +/- blade_j
  float cs[8][8];     // sign of that pair
  int   widx[8][8];   // grade-triple index gi*16+gj*4+gk
  float csf[64];      // sign for flat pair ik = i*8+k
};
constexpr int t_bm(int i){ constexpr int t[8] = {0,1,2,4,3,5,6,7}; return t[i]; }
constexpr int t_idx(int b){ constexpr int t[8] = {0,1,2,4,3,5,6,7}; return t[b]; } // involution
constexpr int t_gr(int i){ constexpr int t[8] = {0,1,1,1,2,2,2,3}; return t[i]; }
constexpr int t_pc(int x){ int c=0; while(x){ c += x&1; x >>= 1; } return c; }
constexpr float t_sign(int a, int b){
  float s = 1.f; int aa = a >> 1;
  while(aa){ if(t_pc(aa & b) & 1) s = -s; aa >>= 1; }
  return s;
}
constexpr Tables mkTables(){
  Tables T{};
  for(int i=0;i<8;i++) for(int k=0;k<8;k++) T.csf[i*8+k] = t_sign(t_bm(i), t_bm(k));
  for(int j=0;j<8;j++) for(int i=0;i<8;i++){
    int k = t_idx(t_bm(i) ^ t_bm(j));
    T.kof[j][i]  = k;
    T.cs[j][i]   = t_sign(t_bm(i), t_bm(k));
    T.widx[j][i] = t_gr(i)*16 + t_gr(j)*4 + t_gr(k);
  }
  return T;
}
__device__ const Tables d_TB = mkTables();

__device__ __forceinline__ float sigf(float z){ return 1.f / (1.f + __expf(-z)); }
__device__ __forceinline__ int gradeOfIdx(int i){ return (i==0)?0:((i<4)?1:((i<7)?2:3)); }

// ---------------- pack_x: x fp32 [b][m][8] -> 8 bf16 planes [i][b*512+m] ----------------
__global__ __launch_bounds__(256) void pack_x(const float* __restrict__ x,
                                              __hip_bfloat16* __restrict__ xP){
  size_t e = (size_t)blockIdx.x*256 + threadIdx.x;   // mv index, 0..2097152
  float4 u0 = *(const float4*)(x + e*8);
  float4 u1 = *(const float4*)(x + e*8 + 4);
  float u[8] = {u0.x,u0.y,u0.z,u0.w,u1.x,u1.y,u1.z,u1.w};
  #pragma unroll
  for(int i=0;i<8;i++) xP[(size_t)i*2097152 + e] = __float2bfloat16(u[i]);
}

// ---------------- pack_w: w fp32 [n][m][4] -> 4 bf16 planes [g][n*512+m] ----------------
__global__ __launch_bounds__(256) void pack_w(const float* __restrict__ w,
                                              __hip_bfloat16* __restrict__ wP){
  size_t e = (size_t)blockIdx.x*256 + threadIdx.x;   // 0..262144
  float4 u = *(const float4*)(w + e*4);
  float v[4] = {u.x,u.y,u.z,u.w};
  #pragma unroll
  for(int g=0; g<4; g++) wP[(size_t)g*262144 + e] = __float2bfloat16(v[g]);
}

// ---------------- K1 MFMA: linrP[i][b][n] = sum_m xP[i][b][m] * wP[g(i)][n][m] ----------------
// 128x128 tile, BK=64, 4 waves (2x2 of 64x64), 16x16x32 bf16 MFMA.
// LDS XOR-swizzle (T2, rule 21): linear global_load_lds dest + pre-swizzled
// global source + swizzled ds_read:  byte ^= ((row&7)<<4).
__global__ __launch_bounds__(256) void k1_mfma(const __hip_bfloat16* __restrict__ xP,
                                               const __hip_bfloat16* __restrict__ wP,
                                               __hip_bfloat16* __restrict__ linrP){
  __shared__ __align__(16) char lds[32768];   // A: [0,16K) rows 128x128B, B: [16K,32K)
  char* As = lds;
  char* Bs = lds + 16384;
  const int tid = threadIdx.x;
  const int l   = tid & 63;
  const int w   = tid >> 6;
  const int i   = blockIdx.z;
  const int g   = gradeOfIdx(i);
  const size_t b0 = (size_t)blockIdx.x * 128;
  const size_t n0 = (size_t)blockIdx.y * 128;
  const __hip_bfloat16* Ag = xP + (size_t)i*2097152;
  const __hip_bfloat16* Bg = wP + (size_t)g*262144;

  const int wave_m = (w & 1) * 64;
  const int wave_n = (w >> 1) * 64;
  const int srow = l >> 3;                       // row within 8-row chunk
  const int scol = ((l & 7) ^ srow) * 8;         // pre-swizzled source col (elems)

  floatx4 acc[4][4] = {};

  for(int kt = 0; kt < 512; kt += 64){
    #pragma unroll
    for(int it=0; it<4; it++){
      int c   = it*4 + w;                        // chunk 0..15 (8 rows each)
      int row = c*8 + srow;
      const __hip_bfloat16* sa = Ag + (b0 + row)*512 + kt + scol;
      const __hip_bfloat16* sb = Bg + (n0 + row)*512 + kt + scol;
      __builtin_amdgcn_global_load_lds((const AS1 void*)sa, (AS3 void*)(As + c*1024 + l*16), 16, 0, 0);
      __builtin_amdgcn_global_load_lds((const AS1 void*)sb, (AS3 void*)(Bs + c*1024 + l*16), 16, 0, 0);
    }
    __syncthreads();
    #pragma unroll
    for(int ks=0; ks<2; ks++){
      short8 af[4], bf[4];
      #pragma unroll
      for(int f=0; f<4; f++){
        int rA = wave_m + f*16 + (l & 15);
        int ca = (ks*64 + (l>>4)*16) ^ ((rA & 7) << 4);
        af[f] = *(const short8*)(As + rA*128 + ca);
        int rB = wave_n + f*16 + (l & 15);
        int cb = (ks*64 + (l>>4)*16) ^ ((rB & 7) << 4);
        bf[f] = *(const short8*)(Bs + rB*128 + cb);
      }
      #pragma unroll
      for(int mf=0; mf<4; mf++){
        #pragma unroll
        for(int nf=0; nf<4; nf++){
          acc[mf][nf] = __builtin_amdgcn_mfma_f32_16x16x32_bf16(af[mf], bf[nf], acc[mf][nf], 0, 0, 0);
        }
      }
    }
    __syncthreads();
  }
  __hip_bfloat16* outp = linrP + (size_t)i*2097152;
  #pragma unroll
  for(int mf=0; mf<4; mf++){
    #pragma unroll
    for(int nf=0; nf<4; nf++){
      #pragma unroll
      for(int r=0; r<4; r++){
        size_t m = wave_m + mf*16 + ((l>>4)<<2) + r;
        size_t n = wave_n + nf*16 + (l & 15);
        outp[(b0+m)*512 + n0+n] = __float2bfloat16(acc[mf][nf][r]);
      }
    }
  }
}

// ---------------- K2: fcgp1 prod + left (partial over n-split) ----------------
#define K2_BT 32
#define K2_NS 4
__global__ __launch_bounds__(256) void k2_prod(const float* __restrict__ x,
                                               const __hip_bfloat16* __restrict__ linr,
                                               const float* __restrict__ norm_a,
                                               const float* __restrict__ gpw,
                                               const float* __restrict__ wl,
                                               float* __restrict__ h1part){
  __shared__ __align__(16) float xv[8][36];   // [i][b]
  __shared__ __align__(16) float xr[8][36];   // [k][b]  (normalized)
  __shared__ __align__(16) float tt[64][36];  // [ik][b] signed pair products
  __shared__ __align__(16) float ws[64][36];  // [triple][m]
  __shared__ __align__(16) float wlt[4][36];  // [g][m]
  const int tid = threadIdx.x;
  const int j  = tid >> 5;
  const int mg = (tid >> 2) & 7;
  const int br = tid & 3;
  const int b0 = blockIdx.x * K2_BT;
  const int n_beg = blockIdx.y * (512 / K2_NS);
  const int n_end = n_beg + (512 / K2_NS);

  int tti[8], wix[8];
  #pragma unroll
  for(int p=0;p<8;p++){
    int k = d_TB.kof[j][p];
    tti[p] = p*8 + k;
    wix[p] = d_TB.widx[j][p];
  }
  const int gj = gradeOfIdx(j);
  const int ikc = tid >> 2;
  const int bqc = (tid & 3) * 8;
  const float csfv = d_TB.csf[ikc];
  const int ic = ikc >> 3, kc = ikc & 7;

  float acc[4][8];
  #pragma unroll
  for(int mi=0;mi<4;mi++){
    #pragma unroll
    for(int b=0;b<8;b++) acc[mi][b] = 0.f;
  }

  for(int n = n_beg; n < n_end; n++){
    // ---- stage ----
    {
      int q0 = tid*2;
      #pragma unroll
      for(int r=0;r<2;r++){
        int q = q0 + r;
        int m = q >> 4, seg = q & 15;
        float4 v = *(const float4*)&gpw[((size_t)m*512 + n)*64 + seg*4];
        ws[seg*4+0][m] = v.x; ws[seg*4+1][m] = v.y;
        ws[seg*4+2][m] = v.z; ws[seg*4+3][m] = v.w;
      }
      if(tid < 32){
        int b = tid;
        const float* px = &x[((size_t)(b0+b)*512 + n)*8];
        float4 u0 = *(const float4*)px, u1 = *(const float4*)(px+4);
        xv[0][b]=u0.x; xv[1][b]=u0.y; xv[2][b]=u0.z; xv[3][b]=u0.w;
        xv[4][b]=u1.x; xv[5][b]=u1.y; xv[6][b]=u1.z; xv[7][b]=u1.w;
      } else if(tid < 64){
        int b = tid - 32;
        size_t e = (size_t)(b0+b)*512 + n;
        float u[8];
        #pragma unroll
        for(int ii=0; ii<8; ii++) u[ii] = __bfloat162float(linr[(size_t)ii*2097152 + e]);
        float4 na = *(const float4*)&norm_a[n*4];
        float s0 = sigf(na.x)*(fabsf(u[0])-1.f)+1.f+1e-6f;
        float s1 = sigf(na.y)*(sqrtf(u[1]*u[1]+u[2]*u[2]+u[3]*u[3])-1.f)+1.f+1e-6f;
        float s2 = sigf(na.z)*(sqrtf(u[4]*u[4]+u[5]*u[5]+u[6]*u[6])-1.f)+1.f+1e-6f;
        float s3 = sigf(na.w)*(fabsf(u[7])-1.f)+1.f+1e-6f;
        xr[0][b]=u[0]/s0; xr[1][b]=u[1]/s1; xr[2][b]=u[2]/s1; xr[3][b]=u[3]/s1;
        xr[4][b]=u[4]/s2; xr[5][b]=u[5]/s2; xr[6][b]=u[6]/s2; xr[7][b]=u[7]/s3;
      } else if(tid < 96){
        int m = tid - 64;
        float4 v = *(const float4*)&wl[((size_t)m*512 + n)*4];
        wlt[0][m]=v.x; wlt[1][m]=v.y; wlt[2][m]=v.z; wlt[3][m]=v.w;
      }
    }
    __syncthreads();
    // ---- signed pair products ----
    {
      float4 a0 = *(const float4*)&xv[ic][bqc];
      float4 a1 = *(const float4*)&xv[ic][bqc+4];
      float4 c0 = *(const float4*)&xr[kc][bqc];
      float4 c1 = *(const float4*)&xr[kc][bqc+4];
      float4 t0, t1;
      t0.x = csfv*a0.x*c0.x; t0.y = csfv*a0.y*c0.y;
      t0.z = csfv*a0.z*c0.z; t0.w = csfv*a0.w*c0.w;
      t1.x = csfv*a1.x*c1.x; t1.y = csfv*a1.y*c1.y;
      t1.z = csfv*a1.z*c1.z; t1.w = csfv*a1.w*c1.w;
      *(float4*)&tt[ikc][bqc]   = t0;
      *(float4*)&tt[ikc][bqc+4] = t1;
    }
    __syncthreads();
    // ---- accumulate ----
    #pragma unroll
    for(int p=0;p<8;p++){
      float4 w4 = *(const float4*)&ws[wix[p]][mg*4];
      float4 t0 = *(const float4*)&tt[tti[p]][br*8];
      float4 t1 = *(const float4*)&tt[tti[p]][br*8+4];
      float tb[8] = {t0.x,t0.y,t0.z,t0.w,t1.x,t1.y,t1.z,t1.w};
      float wm[4] = {w4.x,w4.y,w4.z,w4.w};
      #pragma unroll
      for(int mi=0;mi<4;mi++){
        #pragma unroll
        for(int b=0;b<8;b++) acc[mi][b] = fmaf(wm[mi], tb[b], acc[mi][b]);
      }
    }
    { // left term
      float4 w4 = *(const float4*)&wlt[gj][mg*4];
      float4 x0 = *(const float4*)&xv[j][br*8];
      float4 x1 = *(const float4*)&xv[j][br*8+4];
      float xb[8] = {x0.x,x0.y,x0.z,x0.w,x1.x,x1.y,x1.z,x1.w};
      float wm[4] = {w4.x,w4.y,w4.z,w4.w};
      #pragma unroll
      for(int mi=0;mi<4;mi++){
        #pragma unroll
        for(int b=0;b<8;b++) acc[mi][b] = fmaf(wm[mi], xb[b], acc[mi][b]);
      }
    }
    __syncthreads();
  }
  float* outp = h1part + (size_t)blockIdx.y * (4096u*32u*8u);
  #pragma unroll
  for(int mi=0;mi<4;mi++){
    int m = mg*4 + mi;
    #pragma unroll
    for(int b=0;b<8;b++){
      size_t bb = b0 + br*8 + b;
      outp[(bb*32 + m)*8 + j] = acc[mi][b];
    }
  }
}

// ---------------- K2b: reduce splits + bias + scale + silu -> h1s ----------------
__global__ __launch_bounds__(256) void k2b_silu(const float* __restrict__ h1part,
                                                const float* __restrict__ bl,
                                                const float* __restrict__ sa,
                                                const float* __restrict__ sb,
                                                float* __restrict__ h1s){
  int idx = blockIdx.x*256 + threadIdx.x;  // (b,m)
  int m = idx & 31;
  float v[8];
  #pragma unroll
  for(int h=0;h<2;h++){
    float sx=0.f, sy=0.f, sz=0.f, sw=0.f;
    #pragma unroll
    for(int sp=0; sp<K2_NS; sp++){
      float4 u = *(const float4*)&h1part[(size_t)sp*(4096u*32u*8u) + (size_t)idx*8 + h*4];
      sx+=u.x; sy+=u.y; sz+=u.z; sw+=u.w;
    }
    v[h*4+0]=sx; v[h*4+1]=sy; v[h*4+2]=sz; v[h*4+3]=sw;
  }
  v[0] += bl[m];
  #pragma unroll
  for(int i=0;i<8;i++) v[i] *= INV_SQRT2F;
  float q1 = v[1]*v[1]+v[2]*v[2]+v[3]*v[3];
  float q2 = v[4]*v[4]+v[5]*v[5]+v[6]*v[6];
  float q3 = v[7]*v[7];
  float4 sa4 = *(const float4*)&sa[m*4];
  float4 sb4 = *(const float4*)&sb[m*4];
  float g0 = sigf(sa4.x*v[0] + sb4.x);
  float g1 = sigf(sa4.y*q1   + sb4.y);
  float g2 = sigf(sa4.z*q2   + sb4.z);
  float g3 = sigf(sa4.w*q3   + sb4.w);
  float4 o0 = make_float4(g0*v[0], g1*v[1], g1*v[2], g1*v[3]);
  float4 o1 = make_float4(g2*v[4], g2*v[5], g2*v[6], g3*v[7]);
  *(float4*)&h1s[(size_t)idx*8]     = o0;
  *(float4*)&h1s[(size_t)idx*8 + 4] = o1;
}

// ---------------- K3: sgp + silu + fcgp3 -> out ----------------
__device__ __forceinline__ void linrow32(const float (*src)[32][8], int b, int n,
                                         const float* __restrict__ wr, float* lin){
  for(int m=0;m<32;m++){
    float4 w  = *(const float4*)&wr[(n*32+m)*4];
    float4 h0 = *(const float4*)&src[b][m][0];
    float4 h1 = *(const float4*)&src[b][m][4];
    lin[0] = fmaf(h0.x, w.x, lin[0]);
    lin[1] = fmaf(h0.y, w.y, lin[1]);
    lin[2] = fmaf(h0.z, w.y, lin[2]);
    lin[3] = fmaf(h0.w, w.y, lin[3]);
    lin[4] = fmaf(h1.x, w.z, lin[4]);
    lin[5] = fmaf(h1.y, w.z, lin[5]);
    lin[6] = fmaf(h1.z, w.z, lin[6]);
    lin[7] = fmaf(h1.w, w.w, lin[7]);
  }
}
__device__ __forceinline__ void norm8(float* v, float4 na){
  float s0 = sigf(na.x)*(fabsf(v[0])-1.f)+1.f+1e-6f;
  float s1 = sigf(na.y)*(sqrtf(v[1]*v[1]+v[2]*v[2]+v[3]*v[3])-1.f)+1.f+1e-6f;
  float s2 = sigf(na.z)*(sqrtf(v[4]*v[4]+v[5]*v[5]+v[6]*v[6])-1.f)+1.f+1e-6f;
  float s3 = sigf(na.w)*(fabsf(v[7])-1.f)+1.f+1e-6f;
  v[0]/=s0; v[1]/=s1; v[2]/=s1; v[3]/=s1; v[4]/=s2; v[5]/=s2; v[6]/=s2; v[7]/=s3;
}

__global__ __launch_bounds__(256) void k3_tail(const float* __restrict__ h1s,
    const float* __restrict__ w2r, const float* __restrict__ na2,
    const float* __restrict__ w2l, const float* __restrict__ b2l,
    const float* __restrict__ gw2,
    const float* __restrict__ sa, const float* __restrict__ sb,
    const float* __restrict__ w3r, const float* __restrict__ na3,
    const float* __restrict__ w3l, const float* __restrict__ b3l,
    const float* __restrict__ gw3,
    float* __restrict__ out){
  __shared__ __align__(16) float hs[8][32][8];
  __shared__ __align__(16) float x2[8][32][8];
  __shared__ __align__(16) float h2[8][32][8];
  __shared__ __align__(16) float x3[8][32][8];
  __shared__ __align__(16) float gw2s[32][65];
  const int tid = threadIdx.x;
  const int b0 = blockIdx.x * 8;
  {
    const float4* src = (const float4*)(h1s + (size_t)b0*256);
    float4* dst = (float4*)&hs[0][0][0];
    dst[tid] = src[tid]; dst[tid+256] = src[tid+256];
    const float4* g2 = (const float4*)gw2;
    #pragma unroll
    for(int r=0;r<2;r++){
      float4 v = g2[tid + r*256];
      int flat = (tid + r*256)*4;
      int n = flat >> 6, w = flat & 63;
      gw2s[n][w]=v.x; gw2s[n][w+1]=v.y; gw2s[n][w+2]=v.z; gw2s[n][w+3]=v.w;
    }
  }
  __syncthreads();
  const int b = tid >> 5, n = tid & 31;
  // phase B: lin_r2 + norm -> x2
  {
    float lin[8] = {0,0,0,0,0,0,0,0};
    linrow32(hs, b, n, w2r, lin);
    norm8(lin, *(const float4*)&na2[n*4]);
    *(float4*)&x2[b][n][0] = make_float4(lin[0],lin[1],lin[2],lin[3]);
    *(float4*)&x2[b][n][4] = make_float4(lin[4],lin[5],lin[6],lin[7]);
  }
  __syncthreads();
  // phase C: sgp prod + left + bias + scale + silu -> h2
  {
    float pr[8] = {0,0,0,0,0,0,0,0};
    #pragma unroll
    for(int j=0;j<8;j++){
      #pragma unroll
      for(int i=0;i<8;i++){
        const int k = t_idx(t_bm(i)^t_bm(j));
        const float sgn = t_sign(t_bm(i), t_bm(k));
        const int wix = t_gr(i)*16 + t_gr(j)*4 + t_gr(k);
        pr[j] = fmaf(sgn * hs[b][n][i] * x2[b][n][k], gw2s[n][wix], pr[j]);
      }
    }
    float lf[8] = {0,0,0,0,0,0,0,0};
    linrow32(hs, b, n, w2l, lf);
    float v[8];
    #pragma unroll
    for(int j=0;j<8;j++) v[j] = (pr[j] + lf[j] + ((j==0) ? b2l[n] : 0.f)) * INV_SQRT2F;
    float q1 = v[1]*v[1]+v[2]*v[2]+v[3]*v[3];
    float q2 = v[4]*v[4]+v[5]*v[5]+v[6]*v[6];
    float q3 = v[7]*v[7];
    float4 sa4 = *(const float4*)&sa[n*4];
    float4 sb4 = *(const float4*)&sb[n*4];
    float g0 = sigf(sa4.x*v[0] + sb4.x);
    float g1 = sigf(sa4.y*q1   + sb4.y);
    float g2 = sigf(sa4.z*q2   + sb4.z);
    float g3 = sigf(sa4.w*q3   + sb4.w);
    *(float4*)&h2[b][n][0] = make_float4(g0*v[0], g1*v[1], g1*v[2], g1*v[3]);
    *(float4*)&h2[b][n][4] = make_float4(g2*v[4], g2*v[5], g2*v[6], g3*v[7]);
  }
  __syncthreads();
  // phase D: lin_r3 + norm -> x3
  {
    float lin[8] = {0,0,0,0,0,0,0,0};
    linrow32(h2, b, n, w3r, lin);
    norm8(lin, *(const float4*)&na3[n*4]);
    *(float4*)&x3[b][n][0] = make_float4(lin[0],lin[1],lin[2],lin[3]);
    *(float4*)&x3[b][n][4] = make_float4(lin[4],lin[5],lin[6],lin[7]);
  }
  __syncthreads();
  // phase E: fcgp3 prod + left -> out  (576 outputs per block)
  for(int to = tid; to < 576; to += 256){
    int bb = to / 72;
    int r  = to - bb*72;
    int mo = r >> 3, j = r & 7;
    int kof_r[8], wix_r[8]; float cs_r[8];
    #pragma unroll
    for(int i=0;i<8;i++){
      kof_r[i] = d_TB.kof[j][i];
      cs_r[i]  = d_TB.cs[j][i];
      wix_r[i] = d_TB.widx[j][i];
    }
    const int gj = gradeOfIdx(j);
    float acc = 0.f, accL = 0.f;
    for(int nn=0; nn<32; nn++){
      const float* gp  = &gw3[((size_t)mo*32+nn)*64];
      const float* hh  = &h2[bb][nn][0];
      const float* xrr = &x3[bb][nn][0];
      #pragma unroll
      for(int i=0;i<8;i++)
        acc = fmaf(cs_r[i]*hh[i], xrr[kof_r[i]] * gp[wix_r[i]], acc);
      accL = fmaf(hh[j], w3l[((size_t)mo*32+nn)*4 + gj], accL);
    }
    float res = (acc + accL + ((j==0) ? b3l[mo] : 0.f)) * INV_SQRT2F;
    out[((size_t)(b0+bb)*9 + mo)*8 + j] = res;
  }
}

// ---------------- launch ----------------
extern "C" void kernel_launch(void* const* d_in, const int* in_sizes, int n_in,
                              void* d_out, int out_size, void* d_ws, size_t ws_size,
                              hipStream_t stream){
  const float* x        = (const float*)d_in[0];
  const float* w_right1 = (const float*)d_in[1];
  const float* norm_a1  = (const float*)d_in[2];
  const float* w_left1  = (const float*)d_in[3];
  const float* b_left1  = (const float*)d_in[4];
  const float* gp_w1    = (const float*)d_in[5];
  const float* silu_a   = (const float*)d_in[6];
  const float* silu_b   = (const float*)d_in[7];
  const float* w_right2 = (const float*)d_in[8];
  const float* norm_a2  = (const float*)d_in[9];
  const float* w_left2  = (const float*)d_in[10];
  const float* b_left2  = (const float*)d_in[11];
  const float* gp_w2    = (const float*)d_in[12];
  const float* w_right3 = (const float*)d_in[13];
  const float* norm_a3  = (const float*)d_in[14];
  const float* w_left3  = (const float*)d_in[15];
  const float* b_left3  = (const float*)d_in[16];
  const float* gp_w3    = (const float*)d_in[17];
  float* out = (float*)d_out;

  char* wsb = (char*)d_ws;
  // linrP: bf16 planes [8][4096*512]          -> 33,554,432 B  @ 0
  // xP:    bf16 planes [8][4096*512]          -> 33,554,432 B  @ 33,554,432 (freed after k1)
  // wP:    bf16 planes [4][512*512]           ->  2,097,152 B  @ 67,108,864 (freed after k1)
  // h1part: float [4][4096*32*8] (alias xP)   -> 16,777,216 B  @ 33,554,432
  // h1s:    float [4096*32*8]    (alias xP)   ->  4,194,304 B  @ 50,331,648
  __hip_bfloat16* linrP = (__hip_bfloat16*)wsb;
  __hip_bfloat16* xP    = (__hip_bfloat16*)(wsb + 33554432);
  __hip_bfloat16* wP    = (__hip_bfloat16*)(wsb + 67108864);
  float* h1part = (float*)(wsb + 33554432);
  float* h1s    = (float*)(wsb + 50331648);

  pack_x<<<8192, 256, 0, stream>>>(x, xP);
  pack_w<<<1024, 256, 0, stream>>>(w_right1, wP);
  k1_mfma<<<dim3(32, 4, 8), 256, 0, stream>>>(xP, wP, linrP);
  k2_prod<<<dim3(4096/K2_BT, K2_NS), 256, 0, stream>>>(x, linrP, norm_a1, gp_w1, w_left1, h1part);
  k2b_silu<<<dim3(4096*32/256), 256, 0, stream>>>(h1part, b_left1, silu_a, silu_b, h1s);
  k3_tail<<<dim3(4096/8), 256, 0, stream>>>(h1s,
      w_right2, norm_a2, w_left2, b_left2, gp_w2,
      silu_a, silu_b,
      w_right3, norm_a3, w_left3, b_left3, gp_w3,
      out);
}

// Round 3
// 235.538 us; speedup vs baseline: 2.8801x; 1.9864x over previous
//
#include <hip/hip_runtime.h>
#include <hip/hip_bf16.h>
#include <math.h>

#define INV_SQRT2F 0.70710678118654752440f
#define AS1 __attribute__((address_space(1)))
#define AS3 __attribute__((address_space(3)))

typedef __attribute__((ext_vector_type(8))) short short8;
typedef __attribute__((ext_vector_type(4))) float floatx4;

// ---------------- compile-time algebra tables ----------------
struct Tables {
  int   kof[8][8];    // kof[j][i] = k s.t. blade_i * blade_k = +/- blade_j
  float cs[8][8];     // sign of that pair
  int   widx[8][8];   // grade-triple index gi*16+gj*4+gk
  float csf[64];      // sign for flat pair ik = i*8+k
};
constexpr int t_bm(int i){ constexpr int t[8] = {0,1,2,4,3,5,6,7}; return t[i]; }
constexpr int t_idx(int b){ constexpr int t[8] = {0,1,2,4,3,5,6,7}; return t[b]; } // involution
constexpr int t_gr(int i){ constexpr int t[8] = {0,1,1,1,2,2,2,3}; return t[i]; }
constexpr int t_pc(int x){ int c=0; while(x){ c += x&1; x >>= 1; } return c; }
constexpr float t_sign(int a, int b){
  float s = 1.f; int aa = a >> 1;
  while(aa){ if(t_pc(aa & b) & 1) s = -s; aa >>= 1; }
  return s;
}
constexpr int   c_kof(int j,int i){ return t_idx(t_bm(i)^t_bm(j)); }
constexpr float c_cs(int j,int i){ return t_sign(t_bm(i), t_bm(c_kof(j,i))); }
constexpr int   c_widx(int j,int i){ return t_gr(i)*16 + t_gr(j)*4 + t_gr(c_kof(j,i)); }
constexpr Tables mkTables(){
  Tables T{};
  for(int i=0;i<8;i++) for(int k=0;k<8;k++) T.csf[i*8+k] = t_sign(t_bm(i), t_bm(k));
  for(int j=0;j<8;j++) for(int i=0;i<8;i++){
    T.kof[j][i]  = c_kof(j,i);
    T.cs[j][i]   = c_cs(j,i);
    T.widx[j][i] = c_widx(j,i);
  }
  return T;
}
__device__ const Tables d_TB = mkTables();

__device__ __forceinline__ float sigf(float z){ return 1.f / (1.f + __expf(-z)); }
__device__ __forceinline__ int gradeOfIdx(int i){ return (i==0)?0:((i<4)?1:((i<7)?2:3)); }
__device__ __forceinline__ short f2bf(float v){
  __hip_bfloat16 h = __float2bfloat16(v);
  short s; __builtin_memcpy(&s, &h, 2); return s;
}

// ---------------- pack_x: x fp32 [b][m][8] -> 8 bf16 planes [i][b*512+m] ----------------
__global__ __launch_bounds__(256) void pack_x(const float* __restrict__ x,
                                              __hip_bfloat16* __restrict__ xP){
  size_t e = (size_t)blockIdx.x*256 + threadIdx.x;   // mv index, 0..2097152
  float4 u0 = *(const float4*)(x + e*8);
  float4 u1 = *(const float4*)(x + e*8 + 4);
  float u[8] = {u0.x,u0.y,u0.z,u0.w,u1.x,u1.y,u1.z,u1.w};
  #pragma unroll
  for(int i=0;i<8;i++) xP[(size_t)i*2097152 + e] = __float2bfloat16(u[i]);
}

// ---------------- pack_w: w fp32 [n][m][4] -> 4 bf16 planes [g][n*512+m] ----------------
__global__ __launch_bounds__(256) void pack_w(const float* __restrict__ w,
                                              __hip_bfloat16* __restrict__ wP){
  size_t e = (size_t)blockIdx.x*256 + threadIdx.x;   // 0..262144
  float4 u = *(const float4*)(w + e*4);
  float v[4] = {u.x,u.y,u.z,u.w};
  #pragma unroll
  for(int g=0; g<4; g++) wP[(size_t)g*262144 + e] = __float2bfloat16(v[g]);
}

// ---------------- pack_bw: gpw -> Bpack [j][n][m][i] (sign folded); wl -> wlP [j][m][n] ----------------
__global__ __launch_bounds__(256) void pack_bw(const float* __restrict__ gpw,
                                               const float* __restrict__ wl,
                                               __hip_bfloat16* __restrict__ Bpack,
                                               __hip_bfloat16* __restrict__ wlP){
  int t = blockIdx.x*256 + threadIdx.x;
  if(blockIdx.x < 512){
    // t = j*16384 + n*32 + m
    int j = t >> 14; int n = (t >> 5) & 511; int m = t & 31;
    const float* src = gpw + ((size_t)m*512 + n)*64;
    short8 o;
    #pragma unroll
    for(int jj=0; jj<8; jj++){
      if(jj == j){
        #pragma unroll
        for(int i=0;i<8;i++) o[i] = f2bf(c_cs(jj,i) * src[c_widx(jj,i)]);
      }
    }
    *(short8*)(Bpack + (size_t)t*8) = o;
  } else {
    int t2 = t - 131072;  // j*16384 + m*512 + n
    int j = t2 >> 14; int m = (t2 >> 9) & 31; int n = t2 & 511;
    int g = (j==0)?0:((j<4)?1:((j<7)?2:3));
    wlP[t2] = __float2bfloat16(wl[((size_t)m*512 + n)*4 + g]);
  }
}

// ---------------- K1 MFMA: linrP[i][b][n] = sum_m xP[i][b][m] * wP[g(i)][n][m] ----------------
__global__ __launch_bounds__(256) void k1_mfma(const __hip_bfloat16* __restrict__ xP,
                                               const __hip_bfloat16* __restrict__ wP,
                                               __hip_bfloat16* __restrict__ linrP){
  __shared__ __align__(16) char lds[32768];
  char* As = lds;
  char* Bs = lds + 16384;
  const int tid = threadIdx.x;
  const int l   = tid & 63;
  const int w   = tid >> 6;
  const int i   = blockIdx.z;
  const int g   = gradeOfIdx(i);
  const size_t b0 = (size_t)blockIdx.x * 128;
  const size_t n0 = (size_t)blockIdx.y * 128;
  const __hip_bfloat16* Ag = xP + (size_t)i*2097152;
  const __hip_bfloat16* Bg = wP + (size_t)g*262144;

  const int wave_m = (w & 1) * 64;
  const int wave_n = (w >> 1) * 64;
  const int srow = l >> 3;
  const int scol = ((l & 7) ^ srow) * 8;

  floatx4 acc[4][4] = {};

  for(int kt = 0; kt < 512; kt += 64){
    #pragma unroll
    for(int it=0; it<4; it++){
      int c   = it*4 + w;
      int row = c*8 + srow;
      const __hip_bfloat16* sa = Ag + (b0 + row)*512 + kt + scol;
      const __hip_bfloat16* sb = Bg + (n0 + row)*512 + kt + scol;
      __builtin_amdgcn_global_load_lds((const AS1 void*)sa, (AS3 void*)(As + c*1024 + l*16), 16, 0, 0);
      __builtin_amdgcn_global_load_lds((const AS1 void*)sb, (AS3 void*)(Bs + c*1024 + l*16), 16, 0, 0);
    }
    __syncthreads();
    #pragma unroll
    for(int ks=0; ks<2; ks++){
      short8 af[4], bf[4];
      #pragma unroll
      for(int f=0; f<4; f++){
        int rA = wave_m + f*16 + (l & 15);
        int ca = (ks*64 + (l>>4)*16) ^ ((rA & 7) << 4);
        af[f] = *(const short8*)(As + rA*128 + ca);
        int rB = wave_n + f*16 + (l & 15);
        int cb = (ks*64 + (l>>4)*16) ^ ((rB & 7) << 4);
        bf[f] = *(const short8*)(Bs + rB*128 + cb);
      }
      #pragma unroll
      for(int mf=0; mf<4; mf++){
        #pragma unroll
        for(int nf=0; nf<4; nf++){
          acc[mf][nf] = __builtin_amdgcn_mfma_f32_16x16x32_bf16(af[mf], bf[nf], acc[mf][nf], 0, 0, 0);
        }
      }
    }
    __syncthreads();
  }
  __hip_bfloat16* outp = linrP + (size_t)i*2097152;
  #pragma unroll
  for(int mf=0; mf<4; mf++){
    #pragma unroll
    for(int nf=0; nf<4; nf++){
      #pragma unroll
      for(int r=0; r<4; r++){
        size_t m = wave_m + mf*16 + ((l>>4)<<2) + r;
        size_t n = wave_n + nf*16 + (l & 15);
        outp[(b0+m)*512 + n0+n] = __float2bfloat16(acc[mf][nf][r]);
      }
    }
  }
}

// ---------------- k_left: leftB[j][b][m] = sum_n xP[j][b][n]*wlP[j][m][n]  (MFMA) ----------------
__global__ __launch_bounds__(256) void k_left(const __hip_bfloat16* __restrict__ xP,
                                              const __hip_bfloat16* __restrict__ wlP,
                                              float* __restrict__ leftB){
  const int tid = threadIdx.x;
  const int l = tid & 63, w = tid >> 6;
  const int j = blockIdx.y;
  const int row = blockIdx.x*64 + w*16 + (l & 15);
  floatx4 acc[2] = {};
  const __hip_bfloat16* Ap = xP + (size_t)j*2097152;
  const __hip_bfloat16* Wp = wlP + (size_t)j*16384;
  for(int nc=0; nc<16; nc++){
    int nb = nc*32 + (l>>4)*8;
    short8 a  = *(const short8*)(Ap + (size_t)row*512 + nb);
    short8 b0 = *(const short8*)(Wp + (l&15)*512 + nb);
    short8 b1 = *(const short8*)(Wp + ((l&15)+16)*512 + nb);
    acc[0] = __builtin_amdgcn_mfma_f32_16x16x32_bf16(a, b0, acc[0], 0, 0, 0);
    acc[1] = __builtin_amdgcn_mfma_f32_16x16x32_bf16(a, b1, acc[1], 0, 0, 0);
  }
  #pragma unroll
  for(int mf=0; mf<2; mf++){
    #pragma unroll
    for(int r=0; r<4; r++){
      int b = blockIdx.x*64 + w*16 + (l>>4)*4 + r;
      leftB[(size_t)j*131072 + b*32 + mf*16 + (l&15)] = acc[mf][r];
    }
  }
}

// ---------------- k2_mfma: fcgp1 product via per-j register-built A fragments ----------------
// h1part[sp][j][b][m] partial over n-split sp (64 n each).
__global__ __launch_bounds__(256) void k2_mfma(const float* __restrict__ x,
                                               const __hip_bfloat16* __restrict__ linrP,
                                               const float* __restrict__ norm_a,
                                               const __hip_bfloat16* __restrict__ Bpack,
                                               float* __restrict__ h1part){
  const int tid = threadIdx.x;
  const int l = tid & 63, w = tid >> 6;
  const int row = blockIdx.x*64 + w*16 + (l & 15);
  const int nsb = blockIdx.y * 64;
  floatx4 acc[8][2] = {};

  for(int nc = 0; nc < 16; nc++){
    const int n = nsb + nc*4 + (l>>4);
    const size_t e = (size_t)row*512 + n;
    float4 xa = *(const float4*)(x + e*8);
    float4 xb = *(const float4*)(x + e*8 + 4);
    float xv[8] = {xa.x,xa.y,xa.z,xa.w,xb.x,xb.y,xb.z,xb.w};
    float u[8];
    #pragma unroll
    for(int i=0;i<8;i++) u[i] = __bfloat162float(linrP[(size_t)i*2097152 + e]);
    float4 na = *(const float4*)(norm_a + n*4);
    float s0 = sigf(na.x)*(fabsf(u[0])-1.f)+1.f+1e-6f;
    float s1 = sigf(na.y)*(sqrtf(u[1]*u[1]+u[2]*u[2]+u[3]*u[3])-1.f)+1.f+1e-6f;
    float s2 = sigf(na.z)*(sqrtf(u[4]*u[4]+u[5]*u[5]+u[6]*u[6])-1.f)+1.f+1e-6f;
    float s3 = sigf(na.w)*(fabsf(u[7])-1.f)+1.f+1e-6f;
    float xr[8] = {u[0]/s0, u[1]/s1, u[2]/s1, u[3]/s1,
                   u[4]/s2, u[5]/s2, u[6]/s2, u[7]/s3};
    #pragma unroll
    for(int j=0;j<8;j++){
      short8 af;
      #pragma unroll
      for(int i=0;i<8;i++) af[i] = f2bf(xv[i] * xr[c_kof(j,i)]);
      const __hip_bfloat16* bp = Bpack + (((size_t)j*512 + n)*32)*8;
      short8 b0 = *(const short8*)(bp + (l&15)*8);
      short8 b1 = *(const short8*)(bp + ((l&15)+16)*8);
      acc[j][0] = __builtin_amdgcn_mfma_f32_16x16x32_bf16(af, b0, acc[j][0], 0, 0, 0);
      acc[j][1] = __builtin_amdgcn_mfma_f32_16x16x32_bf16(af, b1, acc[j][1], 0, 0, 0);
    }
  }
  const int sp = blockIdx.y;
  #pragma unroll
  for(int j=0;j<8;j++){
    #pragma unroll
    for(int mf=0; mf<2; mf++){
      #pragma unroll
      for(int r=0; r<4; r++){
        int b = blockIdx.x*64 + w*16 + (l>>4)*4 + r;
        h1part[((size_t)(sp*8+j))*131072 + b*32 + mf*16 + (l&15)] = acc[j][mf][r];
      }
    }
  }
}

// ---------------- K2b: reduce splits + left + bias + scale + silu -> h1s [b][m][8] ----------------
__global__ __launch_bounds__(256) void k2b_silu(const float* __restrict__ h1part,
                                                const float* __restrict__ leftB,
                                                const float* __restrict__ bl,
                                                const float* __restrict__ sa,
                                                const float* __restrict__ sb,
                                                float* __restrict__ h1s){
  int idx = blockIdx.x*256 + threadIdx.x;  // b*32+m
  int m = idx & 31;
  float v[8];
  #pragma unroll
  for(int j=0;j<8;j++){
    float s = leftB[(size_t)j*131072 + idx];
    #pragma unroll
    for(int sp=0; sp<8; sp++) s += h1part[((size_t)(sp*8+j))*131072 + idx];
    v[j] = s;
  }
  v[0] += bl[m];
  #pragma unroll
  for(int i=0;i<8;i++) v[i] *= INV_SQRT2F;
  float q1 = v[1]*v[1]+v[2]*v[2]+v[3]*v[3];
  float q2 = v[4]*v[4]+v[5]*v[5]+v[6]*v[6];
  float q3 = v[7]*v[7];
  float4 sa4 = *(const float4*)&sa[m*4];
  float4 sb4 = *(const float4*)&sb[m*4];
  float g0 = sigf(sa4.x*v[0] + sb4.x);
  float g1 = sigf(sa4.y*q1   + sb4.y);
  float g2 = sigf(sa4.z*q2   + sb4.z);
  float g3 = sigf(sa4.w*q3   + sb4.w);
  float4 o0 = make_float4(g0*v[0], g1*v[1], g1*v[2], g1*v[3]);
  float4 o1 = make_float4(g2*v[4], g2*v[5], g2*v[6], g3*v[7]);
  *(float4*)&h1s[(size_t)idx*8]     = o0;
  *(float4*)&h1s[(size_t)idx*8 + 4] = o1;
}

// ---------------- K3: sgp + silu + fcgp3 -> out ----------------
__device__ __forceinline__ void linrow32(const float (*src)[32][8], int b, int n,
                                         const float* __restrict__ wr, float* lin){
  for(int m=0;m<32;m++){
    float4 w  = *(const float4*)&wr[(n*32+m)*4];
    float4 h0 = *(const float4*)&src[b][m][0];
    float4 h1 = *(const float4*)&src[b][m][4];
    lin[0] = fmaf(h0.x, w.x, lin[0]);
    lin[1] = fmaf(h0.y, w.y, lin[1]);
    lin[2] = fmaf(h0.z, w.y, lin[2]);
    lin[3] = fmaf(h0.w, w.y, lin[3]);
    lin[4] = fmaf(h1.x, w.z, lin[4]);
    lin[5] = fmaf(h1.y, w.z, lin[5]);
    lin[6] = fmaf(h1.z, w.z, lin[6]);
    lin[7] = fmaf(h1.w, w.w, lin[7]);
  }
}
__device__ __forceinline__ void norm8(float* v, float4 na){
  float s0 = sigf(na.x)*(fabsf(v[0])-1.f)+1.f+1e-6f;
  float s1 = sigf(na.y)*(sqrtf(v[1]*v[1]+v[2]*v[2]+v[3]*v[3])-1.f)+1.f+1e-6f;
  float s2 = sigf(na.z)*(sqrtf(v[4]*v[4]+v[5]*v[5]+v[6]*v[6])-1.f)+1.f+1e-6f;
  float s3 = sigf(na.w)*(fabsf(v[7])-1.f)+1.f+1e-6f;
  v[0]/=s0; v[1]/=s1; v[2]/=s1; v[3]/=s1; v[4]/=s2; v[5]/=s2; v[6]/=s2; v[7]/=s3;
}

__global__ __launch_bounds__(256) void k3_tail(const float* __restrict__ h1s,
    const float* __restrict__ w2r, const float* __restrict__ na2,
    const float* __restrict__ w2l, const float* __restrict__ b2l,
    const float* __restrict__ gw2,
    const float* __restrict__ sa, const float* __restrict__ sb,
    const float* __restrict__ w3r, const float* __restrict__ na3,
    const float* __restrict__ w3l, const float* __restrict__ b3l,
    const float* __restrict__ gw3,
    float* __restrict__ out){
  __shared__ __align__(16) float hs[8][32][8];
  __shared__ __align__(16) float x2[8][32][8];
  __shared__ __align__(16) float h2[8][32][8];
  __shared__ __align__(16) float x3[8][32][8];
  __shared__ __align__(16) float gw2s[32][65];
  const int tid = threadIdx.x;
  const int b0 = blockIdx.x * 8;
  {
    const float4* src = (const float4*)(h1s + (size_t)b0*256);
    float4* dst = (float4*)&hs[0][0][0];
    dst[tid] = src[tid]; dst[tid+256] = src[tid+256];
    const float4* g2 = (const float4*)gw2;
    #pragma unroll
    for(int r=0;r<2;r++){
      float4 v = g2[tid + r*256];
      int flat = (tid + r*256)*4;
      int n = flat >> 6, w = flat & 63;
      gw2s[n][w]=v.x; gw2s[n][w+1]=v.y; gw2s[n][w+2]=v.z; gw2s[n][w+3]=v.w;
    }
  }
  __syncthreads();
  const int b = tid >> 5, n = tid & 31;
  {
    float lin[8] = {0,0,0,0,0,0,0,0};
    linrow32(hs, b, n, w2r, lin);
    norm8(lin, *(const float4*)&na2[n*4]);
    *(float4*)&x2[b][n][0] = make_float4(lin[0],lin[1],lin[2],lin[3]);
    *(float4*)&x2[b][n][4] = make_float4(lin[4],lin[5],lin[6],lin[7]);
  }
  __syncthreads();
  {
    float pr[8] = {0,0,0,0,0,0,0,0};
    #pragma unroll
    for(int j=0;j<8;j++){
      #pragma unroll
      for(int i=0;i<8;i++){
        const int k = t_idx(t_bm(i)^t_bm(j));
        const float sgn = t_sign(t_bm(i), t_bm(k));
        const int wix = t_gr(i)*16 + t_gr(j)*4 + t_gr(k);
        pr[j] = fmaf(sgn * hs[b][n][i] * x2[b][n][k], gw2s[n][wix], pr[j]);
      }
    }
    float lf[8] = {0,0,0,0,0,0,0,0};
    linrow32(hs, b, n, w2l, lf);
    float v[8];
    #pragma unroll
    for(int j=0;j<8;j++) v[j] = (pr[j] + lf[j] + ((j==0) ? b2l[n] : 0.f)) * INV_SQRT2F;
    float q1 = v[1]*v[1]+v[2]*v[2]+v[3]*v[3];
    float q2 = v[4]*v[4]+v[5]*v[5]+v[6]*v[6];
    float q3 = v[7]*v[7];
    float4 sa4 = *(const float4*)&sa[n*4];
    float4 sb4 = *(const float4*)&sb[n*4];
    float g0 = sigf(sa4.x*v[0] + sb4.x);
    float g1 = sigf(sa4.y*q1   + sb4.y);
    float g2 = sigf(sa4.z*q2   + sb4.z);
    float g3 = sigf(sa4.w*q3   + sb4.w);
    *(float4*)&h2[b][n][0] = make_float4(g0*v[0], g1*v[1], g1*v[2], g1*v[3]);
    *(float4*)&h2[b][n][4] = make_float4(g2*v[4], g2*v[5], g2*v[6], g3*v[7]);
  }
  __syncthreads();
  {
    float lin[8] = {0,0,0,0,0,0,0,0};
    linrow32(h2, b, n, w3r, lin);
    norm8(lin, *(const float4*)&na3[n*4]);
    *(float4*)&x3[b][n][0] = make_float4(lin[0],lin[1],lin[2],lin[3]);
    *(float4*)&x3[b][n][4] = make_float4(lin[4],lin[5],lin[6],lin[7]);
  }
  __syncthreads();
  for(int to = tid; to < 576; to += 256){
    int bb = to / 72;
    int r  = to - bb*72;
    int mo = r >> 3, j = r & 7;
    int kof_r[8], wix_r[8]; float cs_r[8];
    #pragma unroll
    for(int i=0;i<8;i++){
      kof_r[i] = d_TB.kof[j][i];
      cs_r[i]  = d_TB.cs[j][i];
      wix_r[i] = d_TB.widx[j][i];
    }
    const int gj = gradeOfIdx(j);
    float acc = 0.f, accL = 0.f;
    for(int nn=0; nn<32; nn++){
      const float* gp  = &gw3[((size_t)mo*32+nn)*64];
      const float* hh  = &h2[bb][nn][0];
      const float* xrr = &x3[bb][nn][0];
      #pragma unroll
      for(int i=0;i<8;i++)
        acc = fmaf(cs_r[i]*hh[i], xrr[kof_r[i]] * gp[wix_r[i]], acc);
      accL = fmaf(hh[j], w3l[((size_t)mo*32+nn)*4 + gj], accL);
    }
    float res = (acc + accL + ((j==0) ? b3l[mo] : 0.f)) * INV_SQRT2F;
    out[((size_t)(b0+bb)*9 + mo)*8 + j] = res;
  }
}

// ---------------- launch ----------------
extern "C" void kernel_launch(void* const* d_in, const int* in_sizes, int n_in,
                              void* d_out, int out_size, void* d_ws, size_t ws_size,
                              hipStream_t stream){
  const float* x        = (const float*)d_in[0];
  const float* w_right1 = (const float*)d_in[1];
  const float* norm_a1  = (const float*)d_in[2];
  const float* w_left1  = (const float*)d_in[3];
  const float* b_left1  = (const float*)d_in[4];
  const float* gp_w1    = (const float*)d_in[5];
  const float* silu_a   = (const float*)d_in[6];
  const float* silu_b   = (const float*)d_in[7];
  const float* w_right2 = (const float*)d_in[8];
  const float* norm_a2  = (const float*)d_in[9];
  const float* w_left2  = (const float*)d_in[10];
  const float* b_left2  = (const float*)d_in[11];
  const float* gp_w2    = (const float*)d_in[12];
  const float* w_right3 = (const float*)d_in[13];
  const float* norm_a3  = (const float*)d_in[14];
  const float* w_left3  = (const float*)d_in[15];
  const float* b_left3  = (const float*)d_in[16];
  const float* gp_w3    = (const float*)d_in[17];
  float* out = (float*)d_out;

  char* wsb = (char*)d_ws;
  // ws layout (total ~82.05 MB):
  //  [0,            33,554,432)  xP bf16 planes [8][2M]   ... h1part f32 [8][8][4096][32] aliases after k_left
  //  [33,554,432,   35,651,584)  wP bf16 planes [4][256K]  (dead after k1)
  //  [33,554,432,   37,748,736)  h1s f32 [4096][32][8]     (aliases wP, written by k2b)
  //  [41,943,040,   75,497,472)  linrP bf16 planes [8][2M]
  //  [75,497,472,   77,594,624)  Bpack bf16 [8][512][32][8]
  //  [77,594,624,   77,856,768)  wlP bf16 [8][32][512]
  //  [77,856,768,   82,051,072)  leftB f32 [8][4096][32]
  __hip_bfloat16* xP    = (__hip_bfloat16*)wsb;
  __hip_bfloat16* wP    = (__hip_bfloat16*)(wsb + 33554432);
  float*          h1s   = (float*)(wsb + 33554432);
  __hip_bfloat16* linrP = (__hip_bfloat16*)(wsb + 41943040);
  __hip_bfloat16* Bpack = (__hip_bfloat16*)(wsb + 75497472);
  __hip_bfloat16* wlP   = (__hip_bfloat16*)(wsb + 77594624);
  float*          leftB = (float*)(wsb + 77856768);
  float*          h1part= (float*)wsb;   // aliases xP after k_left

  pack_x<<<8192, 256, 0, stream>>>(x, xP);
  pack_w<<<1024, 256, 0, stream>>>(w_right1, wP);
  pack_bw<<<1024, 256, 0, stream>>>(gp_w1, w_left1, Bpack, wlP);
  k1_mfma<<<dim3(32, 4, 8), 256, 0, stream>>>(xP, wP, linrP);
  k_left<<<dim3(64, 8), 256, 0, stream>>>(xP, wlP, leftB);
  k2_mfma<<<dim3(64, 8), 256, 0, stream>>>(x, linrP, norm_a1, Bpack, h1part);
  k2b_silu<<<512, 256, 0, stream>>>(h1part, leftB, b_left1, silu_a, silu_b, h1s);
  k3_tail<<<dim3(4096/8), 256, 0, stream>>>(h1s,
      w_right2, norm_a2, w_left2, b_left2, gp_w2,
      silu_a, silu_b,
      w_right3, norm_a3, w_left3, b_left3, gp_w3,
      out);
}

// Round 4
// 181.135 us; speedup vs baseline: 3.7451x; 1.3003x over previous
//
#include <hip/hip_runtime.h>
#include <hip/hip_bf16.h>
#include <math.h>

#define INV_SQRT2F 0.70710678118654752440f
#define AS1 __attribute__((address_space(1)))
#define AS3 __attribute__((address_space(3)))

typedef __attribute__((ext_vector_type(8))) short short8;
typedef __attribute__((ext_vector_type(4))) float floatx4;

// ---------------- compile-time algebra tables ----------------
struct Tables {
  int   kof[8][8];    // kof[j][i] = k s.t. blade_i * blade_k = +/- blade_j
  float cs[8][8];     // sign of that pair
  int   widx[8][8];   // grade-triple index gi*16+gj*4+gk
};
constexpr int t_bm(int i){ constexpr int t[8] = {0,1,2,4,3,5,6,7}; return t[i]; }
constexpr int t_idx(int b){ constexpr int t[8] = {0,1,2,4,3,5,6,7}; return t[b]; } // involution
constexpr int t_gr(int i){ constexpr int t[8] = {0,1,1,1,2,2,2,3}; return t[i]; }
constexpr int t_pc(int x){ int c=0; while(x){ c += x&1; x >>= 1; } return c; }
constexpr float t_sign(int a, int b){
  float s = 1.f; int aa = a >> 1;
  while(aa){ if(t_pc(aa & b) & 1) s = -s; aa >>= 1; }
  return s;
}
constexpr int   c_kof(int j,int i){ return t_idx(t_bm(i)^t_bm(j)); }
constexpr float c_cs(int j,int i){ return t_sign(t_bm(i), t_bm(c_kof(j,i))); }
constexpr int   c_widx(int j,int i){ return t_gr(i)*16 + t_gr(j)*4 + t_gr(c_kof(j,i)); }
constexpr Tables mkTables(){
  Tables T{};
  for(int j=0;j<8;j++) for(int i=0;i<8;i++){
    T.kof[j][i]  = c_kof(j,i);
    T.cs[j][i]   = c_cs(j,i);
    T.widx[j][i] = c_widx(j,i);
  }
  return T;
}
__device__ const Tables d_TB = mkTables();

__device__ __forceinline__ float sigf(float z){ return 1.f / (1.f + __expf(-z)); }
__device__ __forceinline__ int gradeOfIdx(int i){ return (i==0)?0:((i<4)?1:((i<7)?2:3)); }
__device__ __forceinline__ short f2bf(float v){
  __hip_bfloat16 h = __float2bfloat16(v);
  short s; __builtin_memcpy(&s, &h, 2); return s;
}
__device__ __forceinline__ void norm8v(float* v, float4 na){
  float s0 = sigf(na.x)*(fabsf(v[0])-1.f)+1.f+1e-6f;
  float s1 = sigf(na.y)*(sqrtf(v[1]*v[1]+v[2]*v[2]+v[3]*v[3])-1.f)+1.f+1e-6f;
  float s2 = sigf(na.z)*(sqrtf(v[4]*v[4]+v[5]*v[5]+v[6]*v[6])-1.f)+1.f+1e-6f;
  float s3 = sigf(na.w)*(fabsf(v[7])-1.f)+1.f+1e-6f;
  v[0]/=s0; v[1]/=s1; v[2]/=s1; v[3]/=s1; v[4]/=s2; v[5]/=s2; v[6]/=s2; v[7]/=s3;
}

// ---------------- pack_x: x fp32 [b][m][8] -> 8 bf16 planes [i][b*512+m] ----------------
__global__ __launch_bounds__(256) void pack_x(const float* __restrict__ x,
                                              __hip_bfloat16* __restrict__ xP){
  size_t e = (size_t)blockIdx.x*256 + threadIdx.x;
  float4 u0 = *(const float4*)(x + e*8);
  float4 u1 = *(const float4*)(x + e*8 + 4);
  float u[8] = {u0.x,u0.y,u0.z,u0.w,u1.x,u1.y,u1.z,u1.w};
  #pragma unroll
  for(int i=0;i<8;i++) xP[(size_t)i*2097152 + e] = __float2bfloat16(u[i]);
}

// ---------------- pack_w: w fp32 [n][m][4] -> 4 bf16 planes [g][n*512+m] ----------------
__global__ __launch_bounds__(256) void pack_w(const float* __restrict__ w,
                                              __hip_bfloat16* __restrict__ wP){
  size_t e = (size_t)blockIdx.x*256 + threadIdx.x;
  float4 u = *(const float4*)(w + e*4);
  float v[4] = {u.x,u.y,u.z,u.w};
  #pragma unroll
  for(int g=0; g<4; g++) wP[(size_t)g*262144 + e] = __float2bfloat16(v[g]);
}

// ---------------- pack_bw: gpw1 -> Bpack [j][n][m][i]; wl1 -> wlP [j][m][n] ----------------
__global__ __launch_bounds__(256) void pack_bw(const float* __restrict__ gpw,
                                               const float* __restrict__ wl,
                                               __hip_bfloat16* __restrict__ Bpack,
                                               __hip_bfloat16* __restrict__ wlP){
  int t = blockIdx.x*256 + threadIdx.x;
  if(blockIdx.x < 512){
    int j = t >> 14; int n = (t >> 5) & 511; int m = t & 31;
    const float* src = gpw + ((size_t)m*512 + n)*64;
    short8 o;
    #pragma unroll
    for(int jj=0; jj<8; jj++){
      if(jj == j){
        #pragma unroll
        for(int i=0;i<8;i++) o[i] = f2bf(c_cs(jj,i) * src[c_widx(jj,i)]);
      }
    }
    *(short8*)(Bpack + (size_t)t*8) = o;
  } else {
    int t2 = t - 131072;  // j*16384 + m*512 + n
    int j = t2 >> 14; int m = (t2 >> 9) & 31; int n = t2 & 511;
    int g = (j==0)?0:((j<4)?1:((j<7)?2:3));
    wlP[t2] = __float2bfloat16(wl[((size_t)m*512 + n)*4 + g]);
  }
}

// ---------------- pack_tail: tail weight packs ----------------
// w2rP/w2lP/w3rP: [j][n][m] bf16 (1024 each per j). Bp3: [j][mo(16)][k(288)]:
// k<256: cs(j,i)*gw3[mo][n][widx]  (k=n*8+i);  k>=256: w3l[mo][n=k-256][g(j)]; mo>=9 -> 0.
__global__ __launch_bounds__(256) void pack_tail(const float* __restrict__ w2r,
                                                 const float* __restrict__ w2l,
                                                 const float* __restrict__ w3r,
                                                 const float* __restrict__ gw3,
                                                 const float* __restrict__ w3l,
                                                 __hip_bfloat16* __restrict__ w2rP,
                                                 __hip_bfloat16* __restrict__ w2lP,
                                                 __hip_bfloat16* __restrict__ w3rP,
                                                 __hip_bfloat16* __restrict__ Bp3){
  int t = blockIdx.x*256 + threadIdx.x;
  if(t < 24576){
    int which = t >> 13; int r = t & 8191;
    int j = r >> 10; int n = (r >> 5) & 31; int m = r & 31;
    int g = gradeOfIdx(j);
    const float* src = (which==0) ? w2r : (which==1) ? w2l : w3r;
    __hip_bfloat16* dst = (which==0) ? w2rP : (which==1) ? w2lP : w3rP;
    dst[r] = __float2bfloat16(src[((size_t)n*32 + m)*4 + g]);
  } else {
    int t2 = t - 24576;             // j*4608 + mo*288 + k
    int j = t2 / 4608; int rem = t2 - j*4608;
    int mo = rem / 288; int k = rem - mo*288;
    float v = 0.f;
    if(mo < 9){
      if(k < 256){
        int n = k >> 3, i = k & 7;
        v = d_TB.cs[j][i] * gw3[((size_t)mo*32 + n)*64 + d_TB.widx[j][i]];
      } else {
        int n = k - 256;
        v = w3l[((size_t)mo*32 + n)*4 + gradeOfIdx(j)];
      }
    }
    Bp3[t2] = __float2bfloat16(v);
  }
}

// ---------------- K1 MFMA: linrP[i][b][n] = sum_m xP[i][b][m] * wP[g(i)][n][m] ----------------
__global__ __launch_bounds__(256) void k1_mfma(const __hip_bfloat16* __restrict__ xP,
                                               const __hip_bfloat16* __restrict__ wP,
                                               __hip_bfloat16* __restrict__ linrP){
  __shared__ __align__(16) char lds[32768];
  char* As = lds;
  char* Bs = lds + 16384;
  const int tid = threadIdx.x;
  const int l   = tid & 63;
  const int w   = tid >> 6;
  const int i   = blockIdx.z;
  const int g   = gradeOfIdx(i);
  const size_t b0 = (size_t)blockIdx.x * 128;
  const size_t n0 = (size_t)blockIdx.y * 128;
  const __hip_bfloat16* Ag = xP + (size_t)i*2097152;
  const __hip_bfloat16* Bg = wP + (size_t)g*262144;

  const int wave_m = (w & 1) * 64;
  const int wave_n = (w >> 1) * 64;
  const int srow = l >> 3;
  const int scol = ((l & 7) ^ srow) * 8;

  floatx4 acc[4][4] = {};

  for(int kt = 0; kt < 512; kt += 64){
    #pragma unroll
    for(int it=0; it<4; it++){
      int c   = it*4 + w;
      int row = c*8 + srow;
      const __hip_bfloat16* sa = Ag + (b0 + row)*512 + kt + scol;
      const __hip_bfloat16* sb = Bg + (n0 + row)*512 + kt + scol;
      __builtin_amdgcn_global_load_lds((const AS1 void*)sa, (AS3 void*)(As + c*1024 + l*16), 16, 0, 0);
      __builtin_amdgcn_global_load_lds((const AS1 void*)sb, (AS3 void*)(Bs + c*1024 + l*16), 16, 0, 0);
    }
    __syncthreads();
    #pragma unroll
    for(int ks=0; ks<2; ks++){
      short8 af[4], bf[4];
      #pragma unroll
      for(int f=0; f<4; f++){
        int rA = wave_m + f*16 + (l & 15);
        int ca = (ks*64 + (l>>4)*16) ^ ((rA & 7) << 4);
        af[f] = *(const short8*)(As + rA*128 + ca);
        int rB = wave_n + f*16 + (l & 15);
        int cb = (ks*64 + (l>>4)*16) ^ ((rB & 7) << 4);
        bf[f] = *(const short8*)(Bs + rB*128 + cb);
      }
      #pragma unroll
      for(int mf=0; mf<4; mf++){
        #pragma unroll
        for(int nf=0; nf<4; nf++){
          acc[mf][nf] = __builtin_amdgcn_mfma_f32_16x16x32_bf16(af[mf], bf[nf], acc[mf][nf], 0, 0, 0);
        }
      }
    }
    __syncthreads();
  }
  __hip_bfloat16* outp = linrP + (size_t)i*2097152;
  #pragma unroll
  for(int mf=0; mf<4; mf++){
    #pragma unroll
    for(int nf=0; nf<4; nf++){
      #pragma unroll
      for(int r=0; r<4; r++){
        size_t m = wave_m + mf*16 + ((l>>4)<<2) + r;
        size_t n = wave_n + nf*16 + (l & 15);
        outp[(b0+m)*512 + n0+n] = __float2bfloat16(acc[mf][nf][r]);
      }
    }
  }
}

// ---------------- k_left: leftB[j][b][m] = sum_n xP[j][b][n]*wlP[j][m][n]  (MFMA) ----------------
__global__ __launch_bounds__(256) void k_left(const __hip_bfloat16* __restrict__ xP,
                                              const __hip_bfloat16* __restrict__ wlP,
                                              float* __restrict__ leftB){
  const int tid = threadIdx.x;
  const int l = tid & 63, w = tid >> 6;
  const int j = blockIdx.y;
  const int row = blockIdx.x*64 + w*16 + (l & 15);
  floatx4 acc[2] = {};
  const __hip_bfloat16* Ap = xP + (size_t)j*2097152;
  const __hip_bfloat16* Wp = wlP + (size_t)j*16384;
  for(int nc=0; nc<16; nc++){
    int nb = nc*32 + (l>>4)*8;
    short8 a  = *(const short8*)(Ap + (size_t)row*512 + nb);
    short8 b0 = *(const short8*)(Wp + (l&15)*512 + nb);
    short8 b1 = *(const short8*)(Wp + ((l&15)+16)*512 + nb);
    acc[0] = __builtin_amdgcn_mfma_f32_16x16x32_bf16(a, b0, acc[0], 0, 0, 0);
    acc[1] = __builtin_amdgcn_mfma_f32_16x16x32_bf16(a, b1, acc[1], 0, 0, 0);
  }
  #pragma unroll
  for(int mf=0; mf<2; mf++){
    #pragma unroll
    for(int r=0; r<4; r++){
      int b = blockIdx.x*64 + w*16 + (l>>4)*4 + r;
      leftB[(size_t)j*131072 + b*32 + mf*16 + (l&15)] = acc[mf][r];
    }
  }
}

// ---------------- k2_mfma: fcgp1 product via per-j register-built A fragments ----------------
__global__ __launch_bounds__(256) void k2_mfma(const float* __restrict__ x,
                                               const __hip_bfloat16* __restrict__ linrP,
                                               const float* __restrict__ norm_a,
                                               const __hip_bfloat16* __restrict__ Bpack,
                                               float* __restrict__ h1part){
  const int tid = threadIdx.x;
  const int l = tid & 63, w = tid >> 6;
  const int row = blockIdx.x*64 + w*16 + (l & 15);
  const int nsb = blockIdx.y * 64;
  floatx4 acc[8][2] = {};

  for(int nc = 0; nc < 16; nc++){
    const int n = nsb + nc*4 + (l>>4);
    const size_t e = (size_t)row*512 + n;
    float4 xa = *(const float4*)(x + e*8);
    float4 xb = *(const float4*)(x + e*8 + 4);
    float xv[8] = {xa.x,xa.y,xa.z,xa.w,xb.x,xb.y,xb.z,xb.w};
    float u[8];
    #pragma unroll
    for(int i=0;i<8;i++) u[i] = __bfloat162float(linrP[(size_t)i*2097152 + e]);
    float4 na = *(const float4*)(norm_a + n*4);
    float s0 = sigf(na.x)*(fabsf(u[0])-1.f)+1.f+1e-6f;
    float s1 = sigf(na.y)*(sqrtf(u[1]*u[1]+u[2]*u[2]+u[3]*u[3])-1.f)+1.f+1e-6f;
    float s2 = sigf(na.z)*(sqrtf(u[4]*u[4]+u[5]*u[5]+u[6]*u[6])-1.f)+1.f+1e-6f;
    float s3 = sigf(na.w)*(fabsf(u[7])-1.f)+1.f+1e-6f;
    float xr[8] = {u[0]/s0, u[1]/s1, u[2]/s1, u[3]/s1,
                   u[4]/s2, u[5]/s2, u[6]/s2, u[7]/s3};
    #pragma unroll
    for(int j=0;j<8;j++){
      short8 af;
      #pragma unroll
      for(int i=0;i<8;i++) af[i] = f2bf(xv[i] * xr[c_kof(j,i)]);
      const __hip_bfloat16* bp = Bpack + (((size_t)j*512 + n)*32)*8;
      short8 b0 = *(const short8*)(bp + (l&15)*8);
      short8 b1 = *(const short8*)(bp + ((l&15)+16)*8);
      acc[j][0] = __builtin_amdgcn_mfma_f32_16x16x32_bf16(af, b0, acc[j][0], 0, 0, 0);
      acc[j][1] = __builtin_amdgcn_mfma_f32_16x16x32_bf16(af, b1, acc[j][1], 0, 0, 0);
    }
  }
  const int sp = blockIdx.y;
  #pragma unroll
  for(int j=0;j<8;j++){
    #pragma unroll
    for(int mf=0; mf<2; mf++){
      #pragma unroll
      for(int r=0; r<4; r++){
        int b = blockIdx.x*64 + w*16 + (l>>4)*4 + r;
        h1part[((size_t)(sp*8+j))*131072 + b*32 + mf*16 + (l&15)] = acc[j][mf][r];
      }
    }
  }
}

// ---------------- K2b: reduce + left + bias + silu -> h1s f32 + h1P bf16 planes ----------------
__global__ __launch_bounds__(256) void k2b_silu(const float* __restrict__ h1part,
                                                const float* __restrict__ leftB,
                                                const float* __restrict__ bl,
                                                const float* __restrict__ sa,
                                                const float* __restrict__ sb,
                                                float* __restrict__ h1s,
                                                __hip_bfloat16* __restrict__ h1P){
  int idx = blockIdx.x*256 + threadIdx.x;  // b*32+m
  int m = idx & 31;
  float v[8];
  #pragma unroll
  for(int j=0;j<8;j++){
    float s = leftB[(size_t)j*131072 + idx];
    #pragma unroll
    for(int sp=0; sp<8; sp++) s += h1part[((size_t)(sp*8+j))*131072 + idx];
    v[j] = s;
  }
  v[0] += bl[m];
  #pragma unroll
  for(int i=0;i<8;i++) v[i] *= INV_SQRT2F;
  float q1 = v[1]*v[1]+v[2]*v[2]+v[3]*v[3];
  float q2 = v[4]*v[4]+v[5]*v[5]+v[6]*v[6];
  float q3 = v[7]*v[7];
  float4 sa4 = *(const float4*)&sa[m*4];
  float4 sb4 = *(const float4*)&sb[m*4];
  float g0 = sigf(sa4.x*v[0] + sb4.x);
  float g1 = sigf(sa4.y*q1   + sb4.y);
  float g2 = sigf(sa4.z*q2   + sb4.z);
  float g3 = sigf(sa4.w*q3   + sb4.w);
  float o[8] = {g0*v[0], g1*v[1], g1*v[2], g1*v[3], g2*v[4], g2*v[5], g2*v[6], g3*v[7]};
  *(float4*)&h1s[(size_t)idx*8]     = make_float4(o[0],o[1],o[2],o[3]);
  *(float4*)&h1s[(size_t)idx*8 + 4] = make_float4(o[4],o[5],o[6],o[7]);
  #pragma unroll
  for(int j=0;j<8;j++) h1P[(size_t)j*131072 + idx] = __float2bfloat16(o[j]);
}

// ---------------- k3a: linr2/left2 [j][b][n] = sum_m h1P[j][b][m] * w2{r,l}P[j][n][m] ----------------
__global__ __launch_bounds__(256) void k3a(const __hip_bfloat16* __restrict__ h1P,
                                           const __hip_bfloat16* __restrict__ w2rP,
                                           const __hip_bfloat16* __restrict__ w2lP,
                                           float* __restrict__ linr2,
                                           float* __restrict__ left2){
  const int tid = threadIdx.x;
  const int l = tid & 63, w = tid >> 6;
  const int j = blockIdx.y;
  const int row = blockIdx.x*64 + w*16 + (l & 15);
  const int ko = (l>>4)*8;
  short8 a   = *(const short8*)(h1P + (size_t)j*131072 + (size_t)row*32 + ko);
  short8 br0 = *(const short8*)(w2rP + j*1024 + (l&15)*32 + ko);
  short8 br1 = *(const short8*)(w2rP + j*1024 + ((l&15)+16)*32 + ko);
  short8 bl0 = *(const short8*)(w2lP + j*1024 + (l&15)*32 + ko);
  short8 bl1 = *(const short8*)(w2lP + j*1024 + ((l&15)+16)*32 + ko);
  floatx4 aR0 = {}, aR1 = {}, aL0 = {}, aL1 = {};
  aR0 = __builtin_amdgcn_mfma_f32_16x16x32_bf16(a, br0, aR0, 0, 0, 0);
  aR1 = __builtin_amdgcn_mfma_f32_16x16x32_bf16(a, br1, aR1, 0, 0, 0);
  aL0 = __builtin_amdgcn_mfma_f32_16x16x32_bf16(a, bl0, aL0, 0, 0, 0);
  aL1 = __builtin_amdgcn_mfma_f32_16x16x32_bf16(a, bl1, aL1, 0, 0, 0);
  #pragma unroll
  for(int r=0; r<4; r++){
    int b = blockIdx.x*64 + w*16 + (l>>4)*4 + r;
    linr2[(size_t)j*131072 + b*32 + (l&15)]      = aR0[r];
    linr2[(size_t)j*131072 + b*32 + 16 + (l&15)] = aR1[r];
    left2[(size_t)j*131072 + b*32 + (l&15)]      = aL0[r];
    left2[(size_t)j*131072 + b*32 + 16 + (l&15)] = aL1[r];
  }
}

// ---------------- k3b: norm(linr2) -> x2; sgp + left2 + bias + silu -> h2f, h2P ----------------
__global__ __launch_bounds__(256) void k3b(const float* __restrict__ linr2,
                                           const float* __restrict__ left2,
                                           const float* __restrict__ h1s,
                                           const float* __restrict__ na2,
                                           const float* __restrict__ gw2,
                                           const float* __restrict__ b2l,
                                           const float* __restrict__ sa,
                                           const float* __restrict__ sb,
                                           float* __restrict__ h2f,
                                           __hip_bfloat16* __restrict__ h2P){
  int idx = blockIdx.x*256 + threadIdx.x;  // b*32+n
  int n = idx & 31;
  float x2[8];
  #pragma unroll
  for(int j=0;j<8;j++) x2[j] = linr2[(size_t)j*131072 + idx];
  norm8v(x2, *(const float4*)&na2[n*4]);
  float4 h0 = *(const float4*)&h1s[(size_t)idx*8];
  float4 h1 = *(const float4*)&h1s[(size_t)idx*8 + 4];
  float h[8] = {h0.x,h0.y,h0.z,h0.w,h1.x,h1.y,h1.z,h1.w};
  const float* g2 = gw2 + (size_t)n*64;
  float v[8];
  #pragma unroll
  for(int j=0;j<8;j++){
    float pr = 0.f;
    #pragma unroll
    for(int i=0;i<8;i++)
      pr = fmaf(c_cs(j,i) * h[i] * x2[c_kof(j,i)], g2[c_widx(j,i)], pr);
    v[j] = (pr + left2[(size_t)j*131072 + idx] + ((j==0) ? b2l[n] : 0.f)) * INV_SQRT2F;
  }
  float q1 = v[1]*v[1]+v[2]*v[2]+v[3]*v[3];
  float q2 = v[4]*v[4]+v[5]*v[5]+v[6]*v[6];
  float q3 = v[7]*v[7];
  float4 sa4 = *(const float4*)&sa[n*4];
  float4 sb4 = *(const float4*)&sb[n*4];
  float g0 = sigf(sa4.x*v[0] + sb4.x);
  float g1 = sigf(sa4.y*q1   + sb4.y);
  float gg2 = sigf(sa4.z*q2  + sb4.z);
  float g3 = sigf(sa4.w*q3   + sb4.w);
  float o[8] = {g0*v[0], g1*v[1], g1*v[2], g1*v[3], gg2*v[4], gg2*v[5], gg2*v[6], g3*v[7]};
  *(float4*)&h2f[(size_t)idx*8]     = make_float4(o[0],o[1],o[2],o[3]);
  *(float4*)&h2f[(size_t)idx*8 + 4] = make_float4(o[4],o[5],o[6],o[7]);
  #pragma unroll
  for(int j=0;j<8;j++) h2P[(size_t)j*131072 + idx] = __float2bfloat16(o[j]);
}

// ---------------- k3c: linr3[j][b][n] = sum_m h2P[j][b][m] * w3rP[j][n][m] ----------------
__global__ __launch_bounds__(256) void k3c(const __hip_bfloat16* __restrict__ h2P,
                                           const __hip_bfloat16* __restrict__ w3rP,
                                           float* __restrict__ linr3){
  const int tid = threadIdx.x;
  const int l = tid & 63, w = tid >> 6;
  const int j = blockIdx.y;
  const int row = blockIdx.x*64 + w*16 + (l & 15);
  const int ko = (l>>4)*8;
  short8 a   = *(const short8*)(h2P + (size_t)j*131072 + (size_t)row*32 + ko);
  short8 b0  = *(const short8*)(w3rP + j*1024 + (l&15)*32 + ko);
  short8 b1  = *(const short8*)(w3rP + j*1024 + ((l&15)+16)*32 + ko);
  floatx4 a0 = {}, a1 = {};
  a0 = __builtin_amdgcn_mfma_f32_16x16x32_bf16(a, b0, a0, 0, 0, 0);
  a1 = __builtin_amdgcn_mfma_f32_16x16x32_bf16(a, b1, a1, 0, 0, 0);
  #pragma unroll
  for(int r=0; r<4; r++){
    int b = blockIdx.x*64 + w*16 + (l>>4)*4 + r;
    linr3[(size_t)j*131072 + b*32 + (l&15)]      = a0[r];
    linr3[(size_t)j*131072 + b*32 + 16 + (l&15)] = a1[r];
  }
}

// ---------------- k3d: norm(linr3) -> x3; pairP[j][b][n*8+i] = bf16(h2[i]*x3[kof(j,i)]) ----------------
__global__ __launch_bounds__(256) void k3d(const float* __restrict__ linr3,
                                           const float* __restrict__ h2f,
                                           const float* __restrict__ na3,
                                           __hip_bfloat16* __restrict__ pairP){
  int idx = blockIdx.x*256 + threadIdx.x;  // b*32+n
  int n = idx & 31;
  float x3[8];
  #pragma unroll
  for(int j=0;j<8;j++) x3[j] = linr3[(size_t)j*131072 + idx];
  norm8v(x3, *(const float4*)&na3[n*4]);
  float4 h0 = *(const float4*)&h2f[(size_t)idx*8];
  float4 h1 = *(const float4*)&h2f[(size_t)idx*8 + 4];
  float h[8] = {h0.x,h0.y,h0.z,h0.w,h1.x,h1.y,h1.z,h1.w};
  #pragma unroll
  for(int j=0;j<8;j++){
    short8 o;
    #pragma unroll
    for(int i=0;i<8;i++) o[i] = f2bf(h[i] * x3[c_kof(j,i)]);
    *(short8*)(pairP + (size_t)j*1048576 + (size_t)idx*8) = o;
  }
}

// ---------------- k3e: out[b][mo][j] = (sum_k pair/h2 x Bp3 + bias) * c ----------------
__global__ __launch_bounds__(256) void k3e(const __hip_bfloat16* __restrict__ pairP,
                                           const __hip_bfloat16* __restrict__ h2P,
                                           const __hip_bfloat16* __restrict__ Bp3,
                                           const float* __restrict__ b3l,
                                           float* __restrict__ out){
  const int tid = threadIdx.x;
  const int l = tid & 63, w = tid >> 6;
  const int j = blockIdx.y;
  const int row = blockIdx.x*64 + w*16 + (l & 15);
  const int mo = l & 15;
  const int ko = (l>>4)*8;
  floatx4 acc = {};
  const __hip_bfloat16* Ap = pairP + (size_t)j*1048576 + (size_t)row*256;
  const __hip_bfloat16* Bp = Bp3 + (size_t)j*4608 + mo*288;
  #pragma unroll
  for(int kc=0; kc<8; kc++){
    short8 a = *(const short8*)(Ap + kc*32 + ko);
    short8 b = *(const short8*)(Bp + kc*32 + ko);
    acc = __builtin_amdgcn_mfma_f32_16x16x32_bf16(a, b, acc, 0, 0, 0);
  }
  {
    short8 a = *(const short8*)(h2P + (size_t)j*131072 + (size_t)row*32 + ko);
    short8 b = *(const short8*)(Bp + 256 + ko);
    acc = __builtin_amdgcn_mfma_f32_16x16x32_bf16(a, b, acc, 0, 0, 0);
  }
  if(mo < 9){
    #pragma unroll
    for(int r=0; r<4; r++){
      int b = blockIdx.x*64 + w*16 + (l>>4)*4 + r;
      out[((size_t)b*9 + mo)*8 + j] = (acc[r] + ((j==0) ? b3l[mo] : 0.f)) * INV_SQRT2F;
    }
  }
}

// ---------------- launch ----------------
extern "C" void kernel_launch(void* const* d_in, const int* in_sizes, int n_in,
                              void* d_out, int out_size, void* d_ws, size_t ws_size,
                              hipStream_t stream){
  const float* x        = (const float*)d_in[0];
  const float* w_right1 = (const float*)d_in[1];
  const float* norm_a1  = (const float*)d_in[2];
  const float* w_left1  = (const float*)d_in[3];
  const float* b_left1  = (const float*)d_in[4];
  const float* gp_w1    = (const float*)d_in[5];
  const float* silu_a   = (const float*)d_in[6];
  const float* silu_b   = (const float*)d_in[7];
  const float* w_right2 = (const float*)d_in[8];
  const float* norm_a2  = (const float*)d_in[9];
  const float* w_left2  = (const float*)d_in[10];
  const float* b_left2  = (const float*)d_in[11];
  const float* gp_w2    = (const float*)d_in[12];
  const float* w_right3 = (const float*)d_in[13];
  const float* norm_a3  = (const float*)d_in[14];
  const float* w_left3  = (const float*)d_in[15];
  const float* b_left3  = (const float*)d_in[16];
  const float* gp_w3    = (const float*)d_in[17];
  float* out = (float*)d_out;

  char* wsb = (char*)d_ws;
  // ws layout (peak ~82.2 MB, < 88 MB proven in R1):
  //  [0,        33,554,432)  xP bf16 [8][2M]  -> h1part f32 [64][131072] (alias after k_left)
  //  [33,554,432,35,651,584) wP bf16 [4][256K] -> h1P bf16 [8][131072] (alias after k1)
  //  [35,651,584,39,845,888) h1s f32 [131072][8]
  //  [41,943,040,75,497,472) linrP bf16 [8][2M]; after k2_mfma reused:
  //      pairP  @41,943,040 (16M)   linr2 @58,720,256 (4M)   left2 @62,914,560 (4M)
  //      h2f    @67,108,864 (4M)    h2P   @71,303,168 (2M)   linr3 @73,400,320 (4M, overlaps dead Bpack)
  //  [75,497,472,77,594,624) Bpack (dead after k2_mfma)
  //  [77,594,624,77,856,768) wlP   (dead after k_left)
  //  [77,856,768,82,051,072) leftB f32 [8][131072]
  //  [82,051,072,82,173,952) w2rP(16K) w2lP(16K) w3rP(16K) Bp3(72K)
  __hip_bfloat16* xP    = (__hip_bfloat16*)wsb;
  float*          h1part= (float*)wsb;
  __hip_bfloat16* wP    = (__hip_bfloat16*)(wsb + 33554432);
  __hip_bfloat16* h1P   = (__hip_bfloat16*)(wsb + 33554432);
  float*          h1s   = (float*)(wsb + 35651584);
  __hip_bfloat16* linrP = (__hip_bfloat16*)(wsb + 41943040);
  __hip_bfloat16* pairP = (__hip_bfloat16*)(wsb + 41943040);
  float*          linr2 = (float*)(wsb + 58720256);
  float*          left2 = (float*)(wsb + 62914560);
  float*          h2f   = (float*)(wsb + 67108864);
  __hip_bfloat16* h2P   = (__hip_bfloat16*)(wsb + 71303168);
  float*          linr3 = (float*)(wsb + 73400320);
  __hip_bfloat16* Bpack = (__hip_bfloat16*)(wsb + 75497472);
  __hip_bfloat16* wlP   = (__hip_bfloat16*)(wsb + 77594624);
  float*          leftB = (float*)(wsb + 77856768);
  __hip_bfloat16* w2rP  = (__hip_bfloat16*)(wsb + 82051072);
  __hip_bfloat16* w2lP  = (__hip_bfloat16*)(wsb + 82051072 + 16384);
  __hip_bfloat16* w3rP  = (__hip_bfloat16*)(wsb + 82051072 + 32768);
  __hip_bfloat16* Bp3   = (__hip_bfloat16*)(wsb + 82051072 + 49152);

  pack_x<<<8192, 256, 0, stream>>>(x, xP);
  pack_w<<<1024, 256, 0, stream>>>(w_right1, wP);
  pack_bw<<<1024, 256, 0, stream>>>(gp_w1, w_left1, Bpack, wlP);
  pack_tail<<<240, 256, 0, stream>>>(w_right2, w_left2, w_right3, gp_w3, w_left3,
                                     w2rP, w2lP, w3rP, Bp3);
  k1_mfma<<<dim3(32, 4, 8), 256, 0, stream>>>(xP, wP, linrP);
  k_left<<<dim3(64, 8), 256, 0, stream>>>(xP, wlP, leftB);
  k2_mfma<<<dim3(64, 8), 256, 0, stream>>>(x, linrP, norm_a1, Bpack, h1part);
  k2b_silu<<<512, 256, 0, stream>>>(h1part, leftB, b_left1, silu_a, silu_b, h1s, h1P);
  k3a<<<dim3(64, 8), 256, 0, stream>>>(h1P, w2rP, w2lP, linr2, left2);
  k3b<<<512, 256, 0, stream>>>(linr2, left2, h1s, norm_a2, gp_w2, b_left2,
                               silu_a, silu_b, h2f, h2P);
  k3c<<<dim3(64, 8), 256, 0, stream>>>(h2P, w3rP, linr3);
  k3d<<<512, 256, 0, stream>>>(linr3, h2f, norm_a3, pairP);
  k3e<<<dim3(64, 8), 256, 0, stream>>>(pairP, h2P, Bp3, b_left3, out);
}

// Round 5
// 178.847 us; speedup vs baseline: 3.7930x; 1.0128x over previous
//
#include <hip/hip_runtime.h>
#include <hip/hip_bf16.h>
#include <math.h>

#define INV_SQRT2F 0.70710678118654752440f
#define AS1 __attribute__((address_space(1)))
#define AS3 __attribute__((address_space(3)))

typedef __attribute__((ext_vector_type(8))) short short8;
typedef __attribute__((ext_vector_type(4))) float floatx4;

// ---------------- compile-time algebra tables ----------------
struct Tables {
  int   kof[8][8];    // kof[j][i] = k s.t. blade_i * blade_k = +/- blade_j
  float cs[8][8];     // sign of that pair
  int   widx[8][8];   // grade-triple index gi*16+gj*4+gk
};
constexpr int t_bm(int i){ constexpr int t[8] = {0,1,2,4,3,5,6,7}; return t[i]; }
constexpr int t_idx(int b){ constexpr int t[8] = {0,1,2,4,3,5,6,7}; return t[b]; } // involution
constexpr int t_gr(int i){ constexpr int t[8] = {0,1,1,1,2,2,2,3}; return t[i]; }
constexpr int t_pc(int x){ int c=0; while(x){ c += x&1; x >>= 1; } return c; }
constexpr float t_sign(int a, int b){
  float s = 1.f; int aa = a >> 1;
  while(aa){ if(t_pc(aa & b) & 1) s = -s; aa >>= 1; }
  return s;
}
constexpr int   c_kof(int j,int i){ return t_idx(t_bm(i)^t_bm(j)); }
constexpr float c_cs(int j,int i){ return t_sign(t_bm(i), t_bm(c_kof(j,i))); }
constexpr int   c_widx(int j,int i){ return t_gr(i)*16 + t_gr(j)*4 + t_gr(c_kof(j,i)); }
constexpr Tables mkTables(){
  Tables T{};
  for(int j=0;j<8;j++) for(int i=0;i<8;i++){
    T.kof[j][i]  = c_kof(j,i);
    T.cs[j][i]   = c_cs(j,i);
    T.widx[j][i] = c_widx(j,i);
  }
  return T;
}
__device__ const Tables d_TB = mkTables();

__device__ __forceinline__ float rcpf(float v){ return __builtin_amdgcn_rcpf(v); }
__device__ __forceinline__ float sigf(float z){ return rcpf(1.f + __expf(-z)); }
__device__ __forceinline__ int gradeOfIdx(int i){ return (i==0)?0:((i<4)?1:((i<7)?2:3)); }
__device__ __forceinline__ short f2bf(float v){
  __hip_bfloat16 h = __float2bfloat16(v);
  short s; __builtin_memcpy(&s, &h, 2); return s;
}
__device__ __forceinline__ void norm8v(float* v, float4 na){
  float s0 = sigf(na.x)*(fabsf(v[0])-1.f)+1.f+1e-6f;
  float s1 = sigf(na.y)*(sqrtf(v[1]*v[1]+v[2]*v[2]+v[3]*v[3])-1.f)+1.f+1e-6f;
  float s2 = sigf(na.z)*(sqrtf(v[4]*v[4]+v[5]*v[5]+v[6]*v[6])-1.f)+1.f+1e-6f;
  float s3 = sigf(na.w)*(fabsf(v[7])-1.f)+1.f+1e-6f;
  float r0 = rcpf(s0), r1 = rcpf(s1), r2 = rcpf(s2), r3 = rcpf(s3);
  v[0]*=r0; v[1]*=r1; v[2]*=r1; v[3]*=r1; v[4]*=r2; v[5]*=r2; v[6]*=r2; v[7]*=r3;
}

// ---------------- pack_x: x fp32 [b][m][8] -> 8 bf16 planes [i][b*512+m] ----------------
__global__ __launch_bounds__(256) void pack_x(const float* __restrict__ x,
                                              __hip_bfloat16* __restrict__ xP){
  size_t e = (size_t)blockIdx.x*256 + threadIdx.x;
  float4 u0 = *(const float4*)(x + e*8);
  float4 u1 = *(const float4*)(x + e*8 + 4);
  float u[8] = {u0.x,u0.y,u0.z,u0.w,u1.x,u1.y,u1.z,u1.w};
  #pragma unroll
  for(int i=0;i<8;i++) xP[(size_t)i*2097152 + e] = __float2bfloat16(u[i]);
}

// ---------------- pack_misc: fused small weight packs ----------------
// blocks [0,1024): pack_w  w_right1 -> wP 4 bf16 planes [g][n*512+m]
// blocks [1024,1536): Bpack [sp][nc][j][q][m][i] (sign folded, K-major contiguous 16KB/nc)
// blocks [1536,2048): wlP [j][m][n]
// blocks [2048,2144): w2rP/w2lP/w3rP [j][n][m]
// blocks [2144,2288): Bp3 [j][mo(16)][k(288)]
__global__ __launch_bounds__(256) void pack_misc(const float* __restrict__ w,
                                                 const float* __restrict__ gpw,
                                                 const float* __restrict__ wl,
                                                 const float* __restrict__ w2r,
                                                 const float* __restrict__ w2l,
                                                 const float* __restrict__ w3r,
                                                 const float* __restrict__ gw3,
                                                 const float* __restrict__ w3l,
                                                 __hip_bfloat16* __restrict__ wP,
                                                 __hip_bfloat16* __restrict__ Bpack,
                                                 __hip_bfloat16* __restrict__ wlP,
                                                 __hip_bfloat16* __restrict__ w2rP,
                                                 __hip_bfloat16* __restrict__ w2lP,
                                                 __hip_bfloat16* __restrict__ w3rP,
                                                 __hip_bfloat16* __restrict__ Bp3){
  const int bx = blockIdx.x;
  if(bx < 1024){
    size_t e = (size_t)bx*256 + threadIdx.x;
    float4 u = *(const float4*)(w + e*4);
    float v[4] = {u.x,u.y,u.z,u.w};
    #pragma unroll
    for(int g=0; g<4; g++) wP[(size_t)g*262144 + e] = __float2bfloat16(v[g]);
  } else if(bx < 1536){
    int t = (bx-1024)*256 + threadIdx.x;          // j*16384 + n*32 + m
    int j = t >> 14; int n = (t >> 5) & 511; int m = t & 31;
    int sp = n >> 6, nc = (n >> 2) & 15, q = n & 3;
    const float* src = gpw + ((size_t)m*512 + n)*64;
    short8 o;
    #pragma unroll
    for(int jj=0; jj<8; jj++){
      if(jj == j){
        #pragma unroll
        for(int i=0;i<8;i++) o[i] = f2bf(c_cs(jj,i) * src[c_widx(jj,i)]);
      }
    }
    *(short8*)(Bpack + (size_t)(sp*16+nc)*8192 + j*1024 + q*256 + m*8) = o;
  } else if(bx < 2048){
    int t2 = (bx-1536)*256 + threadIdx.x;         // j*16384 + m*512 + n
    int j = t2 >> 14; int m = (t2 >> 9) & 31; int n = t2 & 511;
    int g = gradeOfIdx(j);
    wlP[t2] = __float2bfloat16(wl[((size_t)m*512 + n)*4 + g]);
  } else if(bx < 2144){
    int t = (bx-2048)*256 + threadIdx.x;          // which*8192 + j*1024 + n*32 + m
    int which = t >> 13; int r = t & 8191;
    int j = r >> 10; int n = (r >> 5) & 31; int m = r & 31;
    int g = gradeOfIdx(j);
    const float* src = (which==0) ? w2r : (which==1) ? w2l : w3r;
    __hip_bfloat16* dst = (which==0) ? w2rP : (which==1) ? w2lP : w3rP;
    dst[r] = __float2bfloat16(src[((size_t)n*32 + m)*4 + g]);
  } else {
    int t2 = (bx-2144)*256 + threadIdx.x;         // j*4608 + mo*288 + k
    if(t2 >= 36864) return;
    int j = t2 / 4608; int rem = t2 - j*4608;
    int mo = rem / 288; int k = rem - mo*288;
    float v = 0.f;
    if(mo < 9){
      if(k < 256){
        int n = k >> 3, i = k & 7;
        v = d_TB.cs[j][i] * gw3[((size_t)mo*32 + n)*64 + d_TB.widx[j][i]];
      } else {
        int n = k - 256;
        v = w3l[((size_t)mo*32 + n)*4 + gradeOfIdx(j)];
      }
    }
    Bp3[t2] = __float2bfloat16(v);
  }
}

// ---------------- K1 MFMA: linrP[i][b][n] = sum_m xP[i][b][m] * wP[g(i)][n][m] ----------------
__global__ __launch_bounds__(256) void k1_mfma(const __hip_bfloat16* __restrict__ xP,
                                               const __hip_bfloat16* __restrict__ wP,
                                               __hip_bfloat16* __restrict__ linrP){
  __shared__ __align__(16) char lds[32768];
  char* As = lds;
  char* Bs = lds + 16384;
  const int tid = threadIdx.x;
  const int l   = tid & 63;
  const int w   = tid >> 6;
  const int i   = blockIdx.z;
  const int g   = gradeOfIdx(i);
  const size_t b0 = (size_t)blockIdx.x * 128;
  const size_t n0 = (size_t)blockIdx.y * 128;
  const __hip_bfloat16* Ag = xP + (size_t)i*2097152;
  const __hip_bfloat16* Bg = wP + (size_t)g*262144;

  const int wave_m = (w & 1) * 64;
  const int wave_n = (w >> 1) * 64;
  const int srow = l >> 3;
  const int scol = ((l & 7) ^ srow) * 8;

  floatx4 acc[4][4] = {};

  for(int kt = 0; kt < 512; kt += 64){
    #pragma unroll
    for(int it=0; it<4; it++){
      int c   = it*4 + w;
      int row = c*8 + srow;
      const __hip_bfloat16* sa = Ag + (b0 + row)*512 + kt + scol;
      const __hip_bfloat16* sb = Bg + (n0 + row)*512 + kt + scol;
      __builtin_amdgcn_global_load_lds((const AS1 void*)sa, (AS3 void*)(As + c*1024 + l*16), 16, 0, 0);
      __builtin_amdgcn_global_load_lds((const AS1 void*)sb, (AS3 void*)(Bs + c*1024 + l*16), 16, 0, 0);
    }
    __syncthreads();
    #pragma unroll
    for(int ks=0; ks<2; ks++){
      short8 af[4], bf[4];
      #pragma unroll
      for(int f=0; f<4; f++){
        int rA = wave_m + f*16 + (l & 15);
        int ca = (ks*64 + (l>>4)*16) ^ ((rA & 7) << 4);
        af[f] = *(const short8*)(As + rA*128 + ca);
        int rB = wave_n + f*16 + (l & 15);
        int cb = (ks*64 + (l>>4)*16) ^ ((rB & 7) << 4);
        bf[f] = *(const short8*)(Bs + rB*128 + cb);
      }
      #pragma unroll
      for(int mf=0; mf<4; mf++){
        #pragma unroll
        for(int nf=0; nf<4; nf++){
          acc[mf][nf] = __builtin_amdgcn_mfma_f32_16x16x32_bf16(af[mf], bf[nf], acc[mf][nf], 0, 0, 0);
        }
      }
    }
    __syncthreads();
  }
  __hip_bfloat16* outp = linrP + (size_t)i*2097152;
  #pragma unroll
  for(int mf=0; mf<4; mf++){
    #pragma unroll
    for(int nf=0; nf<4; nf++){
      #pragma unroll
      for(int r=0; r<4; r++){
        size_t m = wave_m + mf*16 + ((l>>4)<<2) + r;
        size_t n = wave_n + nf*16 + (l & 15);
        outp[(b0+m)*512 + n0+n] = __float2bfloat16(acc[mf][nf][r]);
      }
    }
  }
}

// ---------------- k_left: leftB[j][b][m] = sum_n xP[j][b][n]*wlP[j][m][n]  (MFMA) ----------------
__global__ __launch_bounds__(256) void k_left(const __hip_bfloat16* __restrict__ xP,
                                              const __hip_bfloat16* __restrict__ wlP,
                                              float* __restrict__ leftB){
  const int tid = threadIdx.x;
  const int l = tid & 63, w = tid >> 6;
  const int j = blockIdx.y;
  const int row = blockIdx.x*64 + w*16 + (l & 15);
  floatx4 acc[2] = {};
  const __hip_bfloat16* Ap = xP + (size_t)j*2097152;
  const __hip_bfloat16* Wp = wlP + (size_t)j*16384;
  for(int nc=0; nc<16; nc++){
    int nb = nc*32 + (l>>4)*8;
    short8 a  = *(const short8*)(Ap + (size_t)row*512 + nb);
    short8 b0 = *(const short8*)(Wp + (l&15)*512 + nb);
    short8 b1 = *(const short8*)(Wp + ((l&15)+16)*512 + nb);
    acc[0] = __builtin_amdgcn_mfma_f32_16x16x32_bf16(a, b0, acc[0], 0, 0, 0);
    acc[1] = __builtin_amdgcn_mfma_f32_16x16x32_bf16(a, b1, acc[1], 0, 0, 0);
  }
  #pragma unroll
  for(int mf=0; mf<2; mf++){
    #pragma unroll
    for(int r=0; r<4; r++){
      int b = blockIdx.x*64 + w*16 + (l>>4)*4 + r;
      leftB[(size_t)j*131072 + b*32 + mf*16 + (l&15)] = acc[mf][r];
    }
  }
}

// ---------------- k2_mfma: fcgp1 product via per-j register-built A fragments ----------------
// Bpack layout: [sp][nc][j][q][m][i] — 16KB contiguous per (sp,nc).
__global__ __launch_bounds__(256) void k2_mfma(const float* __restrict__ x,
                                               const __hip_bfloat16* __restrict__ linrP,
                                               const float* __restrict__ norm_a,
                                               const __hip_bfloat16* __restrict__ Bpack,
                                               float* __restrict__ h1part){
  const int tid = threadIdx.x;
  const int l = tid & 63, w = tid >> 6;
  const int row = blockIdx.x*64 + w*16 + (l & 15);
  const int nsb = blockIdx.y * 64;
  const int boff = (l>>4)*256 + (l&15)*8;
  floatx4 acc[8][2] = {};

  for(int nc = 0; nc < 16; nc++){
    const int n = nsb + nc*4 + (l>>4);
    const size_t e = (size_t)row*512 + n;
    float4 xa = *(const float4*)(x + e*8);
    float4 xb = *(const float4*)(x + e*8 + 4);
    float xv[8] = {xa.x,xa.y,xa.z,xa.w,xb.x,xb.y,xb.z,xb.w};
    float u[8];
    #pragma unroll
    for(int i=0;i<8;i++) u[i] = __bfloat162float(linrP[(size_t)i*2097152 + e]);
    float4 na = *(const float4*)(norm_a + n*4);
    float s0 = sigf(na.x)*(fabsf(u[0])-1.f)+1.f+1e-6f;
    float s1 = sigf(na.y)*(sqrtf(u[1]*u[1]+u[2]*u[2]+u[3]*u[3])-1.f)+1.f+1e-6f;
    float s2 = sigf(na.z)*(sqrtf(u[4]*u[4]+u[5]*u[5]+u[6]*u[6])-1.f)+1.f+1e-6f;
    float s3 = sigf(na.w)*(fabsf(u[7])-1.f)+1.f+1e-6f;
    float r0 = rcpf(s0), r1 = rcpf(s1), r2 = rcpf(s2), r3 = rcpf(s3);
    float xr[8] = {u[0]*r0, u[1]*r1, u[2]*r1, u[3]*r1,
                   u[4]*r2, u[5]*r2, u[6]*r2, u[7]*r3};
    const __hip_bfloat16* bp_nc = Bpack + (size_t)(blockIdx.y*16 + nc)*8192 + boff;
    #pragma unroll
    for(int j=0;j<8;j++){
      short8 af;
      #pragma unroll
      for(int i=0;i<8;i++) af[i] = f2bf(xv[i] * xr[c_kof(j,i)]);
      short8 b0 = *(const short8*)(bp_nc + j*1024);
      short8 b1 = *(const short8*)(bp_nc + j*1024 + 128);
      acc[j][0] = __builtin_amdgcn_mfma_f32_16x16x32_bf16(af, b0, acc[j][0], 0, 0, 0);
      acc[j][1] = __builtin_amdgcn_mfma_f32_16x16x32_bf16(af, b1, acc[j][1], 0, 0, 0);
    }
  }
  const int sp = blockIdx.y;
  #pragma unroll
  for(int j=0;j<8;j++){
    #pragma unroll
    for(int mf=0; mf<2; mf++){
      #pragma unroll
      for(int r=0; r<4; r++){
        int b = blockIdx.x*64 + w*16 + (l>>4)*4 + r;
        h1part[((size_t)(sp*8+j))*131072 + b*32 + mf*16 + (l&15)] = acc[j][mf][r];
      }
    }
  }
}

// ---------------- K2b: reduce + left + bias + silu -> h1s f32 + h1P bf16 planes ----------------
__global__ __launch_bounds__(256) void k2b_silu(const float* __restrict__ h1part,
                                                const float* __restrict__ leftB,
                                                const float* __restrict__ bl,
                                                const float* __restrict__ sa,
                                                const float* __restrict__ sb,
                                                float* __restrict__ h1s,
                                                __hip_bfloat16* __restrict__ h1P){
  int idx = blockIdx.x*256 + threadIdx.x;  // b*32+m
  int m = idx & 31;
  float v[8];
  #pragma unroll
  for(int j=0;j<8;j++){
    float s = leftB[(size_t)j*131072 + idx];
    #pragma unroll
    for(int sp=0; sp<8; sp++) s += h1part[((size_t)(sp*8+j))*131072 + idx];
    v[j] = s;
  }
  v[0] += bl[m];
  #pragma unroll
  for(int i=0;i<8;i++) v[i] *= INV_SQRT2F;
  float q1 = v[1]*v[1]+v[2]*v[2]+v[3]*v[3];
  float q2 = v[4]*v[4]+v[5]*v[5]+v[6]*v[6];
  float q3 = v[7]*v[7];
  float4 sa4 = *(const float4*)&sa[m*4];
  float4 sb4 = *(const float4*)&sb[m*4];
  float g0 = sigf(sa4.x*v[0] + sb4.x);
  float g1 = sigf(sa4.y*q1   + sb4.y);
  float g2 = sigf(sa4.z*q2   + sb4.z);
  float g3 = sigf(sa4.w*q3   + sb4.w);
  float o[8] = {g0*v[0], g1*v[1], g1*v[2], g1*v[3], g2*v[4], g2*v[5], g2*v[6], g3*v[7]};
  *(float4*)&h1s[(size_t)idx*8]     = make_float4(o[0],o[1],o[2],o[3]);
  *(float4*)&h1s[(size_t)idx*8 + 4] = make_float4(o[4],o[5],o[6],o[7]);
  #pragma unroll
  for(int j=0;j<8;j++) h1P[(size_t)j*131072 + idx] = __float2bfloat16(o[j]);
}

// ---------------- k3a: linr2/left2 [j][b][n] = sum_m h1P[j][b][m] * w2{r,l}P[j][n][m] ----------------
__global__ __launch_bounds__(256) void k3a(const __hip_bfloat16* __restrict__ h1P,
                                           const __hip_bfloat16* __restrict__ w2rP,
                                           const __hip_bfloat16* __restrict__ w2lP,
                                           float* __restrict__ linr2,
                                           float* __restrict__ left2){
  const int tid = threadIdx.x;
  const int l = tid & 63, w = tid >> 6;
  const int j = blockIdx.y;
  const int row = blockIdx.x*64 + w*16 + (l & 15);
  const int ko = (l>>4)*8;
  short8 a   = *(const short8*)(h1P + (size_t)j*131072 + (size_t)row*32 + ko);
  short8 br0 = *(const short8*)(w2rP + j*1024 + (l&15)*32 + ko);
  short8 br1 = *(const short8*)(w2rP + j*1024 + ((l&15)+16)*32 + ko);
  short8 bl0 = *(const short8*)(w2lP + j*1024 + (l&15)*32 + ko);
  short8 bl1 = *(const short8*)(w2lP + j*1024 + ((l&15)+16)*32 + ko);
  floatx4 aR0 = {}, aR1 = {}, aL0 = {}, aL1 = {};
  aR0 = __builtin_amdgcn_mfma_f32_16x16x32_bf16(a, br0, aR0, 0, 0, 0);
  aR1 = __builtin_amdgcn_mfma_f32_16x16x32_bf16(a, br1, aR1, 0, 0, 0);
  aL0 = __builtin_amdgcn_mfma_f32_16x16x32_bf16(a, bl0, aL0, 0, 0, 0);
  aL1 = __builtin_amdgcn_mfma_f32_16x16x32_bf16(a, bl1, aL1, 0, 0, 0);
  #pragma unroll
  for(int r=0; r<4; r++){
    int b = blockIdx.x*64 + w*16 + (l>>4)*4 + r;
    linr2[(size_t)j*131072 + b*32 + (l&15)]      = aR0[r];
    linr2[(size_t)j*131072 + b*32 + 16 + (l&15)] = aR1[r];
    left2[(size_t)j*131072 + b*32 + (l&15)]      = aL0[r];
    left2[(size_t)j*131072 + b*32 + 16 + (l&15)] = aL1[r];
  }
}

// ---------------- k3b: norm(linr2) -> x2; sgp + left2 + bias + silu -> h2f, h2P ----------------
__global__ __launch_bounds__(256) void k3b(const float* __restrict__ linr2,
                                           const float* __restrict__ left2,
                                           const float* __restrict__ h1s,
                                           const float* __restrict__ na2,
                                           const float* __restrict__ gw2,
                                           const float* __restrict__ b2l,
                                           const float* __restrict__ sa,
                                           const float* __restrict__ sb,
                                           float* __restrict__ h2f,
                                           __hip_bfloat16* __restrict__ h2P){
  int idx = blockIdx.x*256 + threadIdx.x;  // b*32+n
  int n = idx & 31;
  float x2[8];
  #pragma unroll
  for(int j=0;j<8;j++) x2[j] = linr2[(size_t)j*131072 + idx];
  norm8v(x2, *(const float4*)&na2[n*4]);
  float4 h0 = *(const float4*)&h1s[(size_t)idx*8];
  float4 h1 = *(const float4*)&h1s[(size_t)idx*8 + 4];
  float h[8] = {h0.x,h0.y,h0.z,h0.w,h1.x,h1.y,h1.z,h1.w};
  const float* g2 = gw2 + (size_t)n*64;
  float v[8];
  #pragma unroll
  for(int j=0;j<8;j++){
    float pr = 0.f;
    #pragma unroll
    for(int i=0;i<8;i++)
      pr = fmaf(c_cs(j,i) * h[i] * x2[c_kof(j,i)], g2[c_widx(j,i)], pr);
    v[j] = (pr + left2[(size_t)j*131072 + idx] + ((j==0) ? b2l[n] : 0.f)) * INV_SQRT2F;
  }
  float q1 = v[1]*v[1]+v[2]*v[2]+v[3]*v[3];
  float q2 = v[4]*v[4]+v[5]*v[5]+v[6]*v[6];
  float q3 = v[7]*v[7];
  float4 sa4 = *(const float4*)&sa[n*4];
  float4 sb4 = *(const float4*)&sb[n*4];
  float g0 = sigf(sa4.x*v[0] + sb4.x);
  float g1 = sigf(sa4.y*q1   + sb4.y);
  float gg2 = sigf(sa4.z*q2  + sb4.z);
  float g3 = sigf(sa4.w*q3   + sb4.w);
  float o[8] = {g0*v[0], g1*v[1], g1*v[2], g1*v[3], gg2*v[4], gg2*v[5], gg2*v[6], g3*v[7]};
  *(float4*)&h2f[(size_t)idx*8]     = make_float4(o[0],o[1],o[2],o[3]);
  *(float4*)&h2f[(size_t)idx*8 + 4] = make_float4(o[4],o[5],o[6],o[7]);
  #pragma unroll
  for(int j=0;j<8;j++) h2P[(size_t)j*131072 + idx] = __float2bfloat16(o[j]);
}

// ---------------- k3c: linr3[j][b][n] = sum_m h2P[j][b][m] * w3rP[j][n][m] ----------------
__global__ __launch_bounds__(256) void k3c(const __hip_bfloat16* __restrict__ h2P,
                                           const __hip_bfloat16* __restrict__ w3rP,
                                           float* __restrict__ linr3){
  const int tid = threadIdx.x;
  const int l = tid & 63, w = tid >> 6;
  const int j = blockIdx.y;
  const int row = blockIdx.x*64 + w*16 + (l & 15);
  const int ko = (l>>4)*8;
  short8 a   = *(const short8*)(h2P + (size_t)j*131072 + (size_t)row*32 + ko);
  short8 b0  = *(const short8*)(w3rP + j*1024 + (l&15)*32 + ko);
  short8 b1  = *(const short8*)(w3rP + j*1024 + ((l&15)+16)*32 + ko);
  floatx4 a0 = {}, a1 = {};
  a0 = __builtin_amdgcn_mfma_f32_16x16x32_bf16(a, b0, a0, 0, 0, 0);
  a1 = __builtin_amdgcn_mfma_f32_16x16x32_bf16(a, b1, a1, 0, 0, 0);
  #pragma unroll
  for(int r=0; r<4; r++){
    int b = blockIdx.x*64 + w*16 + (l>>4)*4 + r;
    linr3[(size_t)j*131072 + b*32 + (l&15)]      = a0[r];
    linr3[(size_t)j*131072 + b*32 + 16 + (l&15)] = a1[r];
  }
}

// ---------------- k3d: norm(linr3) -> x3; pairP[j][b][n*8+i] = bf16(h2[i]*x3[kof(j,i)]) ----------------
__global__ __launch_bounds__(256) void k3d(const float* __restrict__ linr3,
                                           const float* __restrict__ h2f,
                                           const float* __restrict__ na3,
                                           __hip_bfloat16* __restrict__ pairP){
  int idx = blockIdx.x*256 + threadIdx.x;  // b*32+n
  int n = idx & 31;
  float x3[8];
  #pragma unroll
  for(int j=0;j<8;j++) x3[j] = linr3[(size_t)j*131072 + idx];
  norm8v(x3, *(const float4*)&na3[n*4]);
  float4 h0 = *(const float4*)&h2f[(size_t)idx*8];
  float4 h1 = *(const float4*)&h2f[(size_t)idx*8 + 4];
  float h[8] = {h0.x,h0.y,h0.z,h0.w,h1.x,h1.y,h1.z,h1.w};
  #pragma unroll
  for(int j=0;j<8;j++){
    short8 o;
    #pragma unroll
    for(int i=0;i<8;i++) o[i] = f2bf(h[i] * x3[c_kof(j,i)]);
    *(short8*)(pairP + (size_t)j*1048576 + (size_t)idx*8) = o;
  }
}

// ---------------- k3e: out[b][mo][j] = (sum_k pair/h2 x Bp3 + bias) * c ----------------
__global__ __launch_bounds__(256) void k3e(const __hip_bfloat16* __restrict__ pairP,
                                           const __hip_bfloat16* __restrict__ h2P,
                                           const __hip_bfloat16* __restrict__ Bp3,
                                           const float* __restrict__ b3l,
                                           float* __restrict__ out){
  const int tid = threadIdx.x;
  const int l = tid & 63, w = tid >> 6;
  const int j = blockIdx.y;
  const int row = blockIdx.x*64 + w*16 + (l & 15);
  const int mo = l & 15;
  const int ko = (l>>4)*8;
  floatx4 acc = {};
  const __hip_bfloat16* Ap = pairP + (size_t)j*1048576 + (size_t)row*256;
  const __hip_bfloat16* Bp = Bp3 + (size_t)j*4608 + mo*288;
  #pragma unroll
  for(int kc=0; kc<8; kc++){
    short8 a = *(const short8*)(Ap + kc*32 + ko);
    short8 b = *(const short8*)(Bp + kc*32 + ko);
    acc = __builtin_amdgcn_mfma_f32_16x16x32_bf16(a, b, acc, 0, 0, 0);
  }
  {
    short8 a = *(const short8*)(h2P + (size_t)j*131072 + (size_t)row*32 + ko);
    short8 b = *(const short8*)(Bp + 256 + ko);
    acc = __builtin_amdgcn_mfma_f32_16x16x32_bf16(a, b, acc, 0, 0, 0);
  }
  if(mo < 9){
    #pragma unroll
    for(int r=0; r<4; r++){
      int b = blockIdx.x*64 + w*16 + (l>>4)*4 + r;
      out[((size_t)b*9 + mo)*8 + j] = (acc[r] + ((j==0) ? b3l[mo] : 0.f)) * INV_SQRT2F;
    }
  }
}

// ---------------- launch ----------------
extern "C" void kernel_launch(void* const* d_in, const int* in_sizes, int n_in,
                              void* d_out, int out_size, void* d_ws, size_t ws_size,
                              hipStream_t stream){
  const float* x        = (const float*)d_in[0];
  const float* w_right1 = (const float*)d_in[1];
  const float* norm_a1  = (const float*)d_in[2];
  const float* w_left1  = (const float*)d_in[3];
  const float* b_left1  = (const float*)d_in[4];
  const float* gp_w1    = (const float*)d_in[5];
  const float* silu_a   = (const float*)d_in[6];
  const float* silu_b   = (const float*)d_in[7];
  const float* w_right2 = (const float*)d_in[8];
  const float* norm_a2  = (const float*)d_in[9];
  const float* w_left2  = (const float*)d_in[10];
  const float* b_left2  = (const float*)d_in[11];
  const float* gp_w2    = (const float*)d_in[12];
  const float* w_right3 = (const float*)d_in[13];
  const float* norm_a3  = (const float*)d_in[14];
  const float* w_left3  = (const float*)d_in[15];
  const float* b_left3  = (const float*)d_in[16];
  const float* gp_w3    = (const float*)d_in[17];
  float* out = (float*)d_out;

  char* wsb = (char*)d_ws;
  // ws layout (peak ~82.2 MB):
  //  [0,        33,554,432)  xP bf16 [8][2M]  -> h1part f32 [64][131072] (alias after k_left)
  //  [33,554,432,35,651,584) wP bf16 [4][256K] -> h1P bf16 [8][131072] (alias after k1)
  //  [35,651,584,39,845,888) h1s f32 [131072][8]
  //  [41,943,040,75,497,472) linrP bf16 [8][2M]; after k2_mfma reused:
  //      pairP  @41,943,040 (16M)   linr2 @58,720,256 (4M)   left2 @62,914,560 (4M)
  //      h2f    @67,108,864 (4M)    h2P   @71,303,168 (2M)   linr3 @73,400,320 (4M)
  //  [75,497,472,77,594,624) Bpack [sp][nc][j][q][m][i] (dead after k2_mfma)
  //  [77,594,624,77,856,768) wlP   (dead after k_left)
  //  [77,856,768,82,051,072) leftB f32 [8][131072]
  //  [82,051,072,82,173,952) w2rP(16K) w2lP(16K) w3rP(16K) Bp3(72K)
  __hip_bfloat16* xP    = (__hip_bfloat16*)wsb;
  float*          h1part= (float*)wsb;
  __hip_bfloat16* wP    = (__hip_bfloat16*)(wsb + 33554432);
  __hip_bfloat16* h1P   = (__hip_bfloat16*)(wsb + 33554432);
  float*          h1s   = (float*)(wsb + 35651584);
  __hip_bfloat16* linrP = (__hip_bfloat16*)(wsb + 41943040);
  __hip_bfloat16* pairP = (__hip_bfloat16*)(wsb + 41943040);
  float*          linr2 = (float*)(wsb + 58720256);
  float*          left2 = (float*)(wsb + 62914560);
  float*          h2f   = (float*)(wsb + 67108864);
  __hip_bfloat16* h2P   = (__hip_bfloat16*)(wsb + 71303168);
  float*          linr3 = (float*)(wsb + 73400320);
  __hip_bfloat16* Bpack = (__hip_bfloat16*)(wsb + 75497472);
  __hip_bfloat16* wlP   = (__hip_bfloat16*)(wsb + 77594624);
  float*          leftB = (float*)(wsb + 77856768);
  __hip_bfloat16* w2rP  = (__hip_bfloat16*)(wsb + 82051072);
  __hip_bfloat16* w2lP  = (__hip_bfloat16*)(wsb + 82051072 + 16384);
  __hip_bfloat16* w3rP  = (__hip_bfloat16*)(wsb + 82051072 + 32768);
  __hip_bfloat16* Bp3   = (__hip_bfloat16*)(wsb + 82051072 + 49152);

  pack_x<<<8192, 256, 0, stream>>>(x, xP);
  pack_misc<<<2288, 256, 0, stream>>>(w_right1, gp_w1, w_left1,
                                      w_right2, w_left2, w_right3, gp_w3, w_left3,
                                      wP, Bpack, wlP, w2rP, w2lP, w3rP, Bp3);
  k1_mfma<<<dim3(32, 4, 8), 256, 0, stream>>>(xP, wP, linrP);
  k_left<<<dim3(64, 8), 256, 0, stream>>>(xP, wlP, leftB);
  k2_mfma<<<dim3(64, 8), 256, 0, stream>>>(x, linrP, norm_a1, Bpack, h1part);
  k2b_silu<<<512, 256, 0, stream>>>(h1part, leftB, b_left1, silu_a, silu_b, h1s, h1P);
  k3a<<<dim3(64, 8), 256, 0, stream>>>(h1P, w2rP, w2lP, linr2, left2);
  k3b<<<512, 256, 0, stream>>>(linr2, left2, h1s, norm_a2, gp_w2, b_left2,
                               silu_a, silu_b, h2f, h2P);
  k3c<<<dim3(64, 8), 256, 0, stream>>>(h2P, w3rP, linr3);
  k3d<<<512, 256, 0, stream>>>(linr3, h2f, norm_a3, pairP);
  k3e<<<dim3(64, 8), 256, 0, stream>>>(pairP, h2P, Bp3, b_left3, out);
}

// Round 6
// 153.944 us; speedup vs baseline: 4.4066x; 1.1618x over previous
//
#include <hip/hip_runtime.h>
#include <hip/hip_bf16.h>
#include <math.h>

#define INV_SQRT2F 0.70710678118654752440f
#define AS1 __attribute__((address_space(1)))
#define AS3 __attribute__((address_space(3)))

typedef __attribute__((ext_vector_type(8))) short short8;
typedef __attribute__((ext_vector_type(4))) float floatx4;

// ---------------- compile-time algebra tables ----------------
struct Tables {
  int   kof[8][8];
  float cs[8][8];
  int   widx[8][8];
};
constexpr int t_bm(int i){ constexpr int t[8] = {0,1,2,4,3,5,6,7}; return t[i]; }
constexpr int t_idx(int b){ constexpr int t[8] = {0,1,2,4,3,5,6,7}; return t[b]; }
constexpr int t_gr(int i){ constexpr int t[8] = {0,1,1,1,2,2,2,3}; return t[i]; }
constexpr int t_pc(int x){ int c=0; while(x){ c += x&1; x >>= 1; } return c; }
constexpr float t_sign(int a, int b){
  float s = 1.f; int aa = a >> 1;
  while(aa){ if(t_pc(aa & b) & 1) s = -s; aa >>= 1; }
  return s;
}
constexpr int   c_kof(int j,int i){ return t_idx(t_bm(i)^t_bm(j)); }
constexpr float c_cs(int j,int i){ return t_sign(t_bm(i), t_bm(c_kof(j,i))); }
constexpr int   c_widx(int j,int i){ return t_gr(i)*16 + t_gr(j)*4 + t_gr(c_kof(j,i)); }
constexpr Tables mkTables(){
  Tables T{};
  for(int j=0;j<8;j++) for(int i=0;i<8;i++){
    T.kof[j][i]  = c_kof(j,i);
    T.cs[j][i]   = c_cs(j,i);
    T.widx[j][i] = c_widx(j,i);
  }
  return T;
}
__device__ const Tables d_TB = mkTables();

__device__ __forceinline__ float rcpf(float v){ return __builtin_amdgcn_rcpf(v); }
__device__ __forceinline__ float sigf(float z){ return rcpf(1.f + __expf(-z)); }
__device__ __forceinline__ int gradeOfIdx(int i){ return (i==0)?0:((i<4)?1:((i<7)?2:3)); }
__device__ __forceinline__ short f2bf(float v){
  __hip_bfloat16 h = __float2bfloat16(v);
  short s; __builtin_memcpy(&s, &h, 2); return s;
}
__device__ __forceinline__ float bf2f(short s){
  unsigned int w = ((unsigned int)(unsigned short)s) << 16;
  float f; __builtin_memcpy(&f, &w, 4); return f;
}
__device__ __forceinline__ void norm8v(float* v, float4 na){
  float s0 = sigf(na.x)*(fabsf(v[0])-1.f)+1.f+1e-6f;
  float s1 = sigf(na.y)*(sqrtf(v[1]*v[1]+v[2]*v[2]+v[3]*v[3])-1.f)+1.f+1e-6f;
  float s2 = sigf(na.z)*(sqrtf(v[4]*v[4]+v[5]*v[5]+v[6]*v[6])-1.f)+1.f+1e-6f;
  float s3 = sigf(na.w)*(fabsf(v[7])-1.f)+1.f+1e-6f;
  float r0 = rcpf(s0), r1 = rcpf(s1), r2 = rcpf(s2), r3 = rcpf(s3);
  v[0]*=r0; v[1]*=r1; v[2]*=r1; v[3]*=r1; v[4]*=r2; v[5]*=r2; v[6]*=r2; v[7]*=r3;
}

// ---------------- pack_x: x fp32 [b][m][8] -> 8 bf16 planes [i][b*512+m] ----------------
__global__ __launch_bounds__(256) void pack_x(const float* __restrict__ x,
                                              __hip_bfloat16* __restrict__ xP){
  size_t e = (size_t)blockIdx.x*256 + threadIdx.x;
  float4 u0 = *(const float4*)(x + e*8);
  float4 u1 = *(const float4*)(x + e*8 + 4);
  float u[8] = {u0.x,u0.y,u0.z,u0.w,u1.x,u1.y,u1.z,u1.w};
  #pragma unroll
  for(int i=0;i<8;i++) xP[(size_t)i*2097152 + e] = __float2bfloat16(u[i]);
}

// ---------------- pack_misc: fused small weight packs ----------------
__global__ __launch_bounds__(256) void pack_misc(const float* __restrict__ w,
                                                 const float* __restrict__ gpw,
                                                 const float* __restrict__ wl,
                                                 const float* __restrict__ w2r,
                                                 const float* __restrict__ w2l,
                                                 const float* __restrict__ w3r,
                                                 const float* __restrict__ gw3,
                                                 const float* __restrict__ w3l,
                                                 __hip_bfloat16* __restrict__ wP,
                                                 __hip_bfloat16* __restrict__ Bpack,
                                                 __hip_bfloat16* __restrict__ wlP,
                                                 __hip_bfloat16* __restrict__ w2rP,
                                                 __hip_bfloat16* __restrict__ w2lP,
                                                 __hip_bfloat16* __restrict__ w3rP,
                                                 __hip_bfloat16* __restrict__ Bp3){
  const int bx = blockIdx.x;
  if(bx < 1024){
    size_t e = (size_t)bx*256 + threadIdx.x;
    float4 u = *(const float4*)(w + e*4);
    float v[4] = {u.x,u.y,u.z,u.w};
    #pragma unroll
    for(int g=0; g<4; g++) wP[(size_t)g*262144 + e] = __float2bfloat16(v[g]);
  } else if(bx < 1536){
    int t = (bx-1024)*256 + threadIdx.x;          // j*16384 + n*32 + m
    int j = t >> 14; int n = (t >> 5) & 511; int m = t & 31;
    int sp = n >> 6, nc = (n >> 2) & 15, q = n & 3;
    const float* src = gpw + ((size_t)m*512 + n)*64;
    short8 o;
    #pragma unroll
    for(int jj=0; jj<8; jj++){
      if(jj == j){
        #pragma unroll
        for(int i=0;i<8;i++) o[i] = f2bf(c_cs(jj,i) * src[c_widx(jj,i)]);
      }
    }
    *(short8*)(Bpack + (size_t)(sp*16+nc)*8192 + j*1024 + q*256 + m*8) = o;
  } else if(bx < 2048){
    int t2 = (bx-1536)*256 + threadIdx.x;         // j*16384 + m*512 + n
    int j = t2 >> 14; int m = (t2 >> 9) & 31; int n = t2 & 511;
    int g = gradeOfIdx(j);
    wlP[t2] = __float2bfloat16(wl[((size_t)m*512 + n)*4 + g]);
  } else if(bx < 2144){
    int t = (bx-2048)*256 + threadIdx.x;
    int which = t >> 13; int r = t & 8191;
    int j = r >> 10; int n = (r >> 5) & 31; int m = r & 31;
    int g = gradeOfIdx(j);
    const float* src = (which==0) ? w2r : (which==1) ? w2l : w3r;
    __hip_bfloat16* dst = (which==0) ? w2rP : (which==1) ? w2lP : w3rP;
    dst[r] = __float2bfloat16(src[((size_t)n*32 + m)*4 + g]);
  } else {
    int t2 = (bx-2144)*256 + threadIdx.x;         // j*4608 + mo*288 + k
    if(t2 >= 36864) return;
    int j = t2 / 4608; int rem = t2 - j*4608;
    int mo = rem / 288; int k = rem - mo*288;
    float v = 0.f;
    if(mo < 9){
      if(k < 256){
        int n = k >> 3, i = k & 7;
        v = d_TB.cs[j][i] * gw3[((size_t)mo*32 + n)*64 + d_TB.widx[j][i]];
      } else {
        int n = k - 256;
        v = w3l[((size_t)mo*32 + n)*4 + gradeOfIdx(j)];
      }
    }
    Bp3[t2] = __float2bfloat16(v);
  }
}

// ---------------- K1 MFMA: linrP[i][b][n] = sum_m xP[i][b][m] * wP[g(i)][n][m] ----------------
__global__ __launch_bounds__(256) void k1_mfma(const __hip_bfloat16* __restrict__ xP,
                                               const __hip_bfloat16* __restrict__ wP,
                                               __hip_bfloat16* __restrict__ linrP){
  __shared__ __align__(16) char lds[32768];
  char* As = lds;
  char* Bs = lds + 16384;
  const int tid = threadIdx.x;
  const int l   = tid & 63;
  const int w   = tid >> 6;
  const int i   = blockIdx.z;
  const int g   = gradeOfIdx(i);
  const size_t b0 = (size_t)blockIdx.x * 128;
  const size_t n0 = (size_t)blockIdx.y * 128;
  const __hip_bfloat16* Ag = xP + (size_t)i*2097152;
  const __hip_bfloat16* Bg = wP + (size_t)g*262144;

  const int wave_m = (w & 1) * 64;
  const int wave_n = (w >> 1) * 64;
  const int srow = l >> 3;
  const int scol = ((l & 7) ^ srow) * 8;

  floatx4 acc[4][4] = {};

  for(int kt = 0; kt < 512; kt += 64){
    #pragma unroll
    for(int it=0; it<4; it++){
      int c   = it*4 + w;
      int row = c*8 + srow;
      const __hip_bfloat16* sa = Ag + (b0 + row)*512 + kt + scol;
      const __hip_bfloat16* sb = Bg + (n0 + row)*512 + kt + scol;
      __builtin_amdgcn_global_load_lds((const AS1 void*)sa, (AS3 void*)(As + c*1024 + l*16), 16, 0, 0);
      __builtin_amdgcn_global_load_lds((const AS1 void*)sb, (AS3 void*)(Bs + c*1024 + l*16), 16, 0, 0);
    }
    __syncthreads();
    #pragma unroll
    for(int ks=0; ks<2; ks++){
      short8 af[4], bf[4];
      #pragma unroll
      for(int f=0; f<4; f++){
        int rA = wave_m + f*16 + (l & 15);
        int ca = (ks*64 + (l>>4)*16) ^ ((rA & 7) << 4);
        af[f] = *(const short8*)(As + rA*128 + ca);
        int rB = wave_n + f*16 + (l & 15);
        int cb = (ks*64 + (l>>4)*16) ^ ((rB & 7) << 4);
        bf[f] = *(const short8*)(Bs + rB*128 + cb);
      }
      #pragma unroll
      for(int mf=0; mf<4; mf++){
        #pragma unroll
        for(int nf=0; nf<4; nf++){
          acc[mf][nf] = __builtin_amdgcn_mfma_f32_16x16x32_bf16(af[mf], bf[nf], acc[mf][nf], 0, 0, 0);
        }
      }
    }
    __syncthreads();
  }
  __hip_bfloat16* outp = linrP + (size_t)i*2097152;
  #pragma unroll
  for(int mf=0; mf<4; mf++){
    #pragma unroll
    for(int nf=0; nf<4; nf++){
      #pragma unroll
      for(int r=0; r<4; r++){
        size_t m = wave_m + mf*16 + ((l>>4)<<2) + r;
        size_t n = wave_n + nf*16 + (l & 15);
        outp[(b0+m)*512 + n0+n] = __float2bfloat16(acc[mf][nf][r]);
      }
    }
  }
}

// ---------------- k_left: leftB[j][b][m] = sum_n xP[j][b][n]*wlP[j][m][n]  (MFMA) ----------------
__global__ __launch_bounds__(256) void k_left(const __hip_bfloat16* __restrict__ xP,
                                              const __hip_bfloat16* __restrict__ wlP,
                                              float* __restrict__ leftB){
  const int tid = threadIdx.x;
  const int l = tid & 63, w = tid >> 6;
  const int j = blockIdx.y;
  const int row = blockIdx.x*64 + w*16 + (l & 15);
  floatx4 acc[2] = {};
  const __hip_bfloat16* Ap = xP + (size_t)j*2097152;
  const __hip_bfloat16* Wp = wlP + (size_t)j*16384;
  for(int nc=0; nc<16; nc++){
    int nb = nc*32 + (l>>4)*8;
    short8 a  = *(const short8*)(Ap + (size_t)row*512 + nb);
    short8 b0 = *(const short8*)(Wp + (l&15)*512 + nb);
    short8 b1 = *(const short8*)(Wp + ((l&15)+16)*512 + nb);
    acc[0] = __builtin_amdgcn_mfma_f32_16x16x32_bf16(a, b0, acc[0], 0, 0, 0);
    acc[1] = __builtin_amdgcn_mfma_f32_16x16x32_bf16(a, b1, acc[1], 0, 0, 0);
  }
  #pragma unroll
  for(int mf=0; mf<2; mf++){
    #pragma unroll
    for(int r=0; r<4; r++){
      int b = blockIdx.x*64 + w*16 + (l>>4)*4 + r;
      leftB[(size_t)j*131072 + b*32 + mf*16 + (l&15)] = acc[mf][r];
    }
  }
}

// ---------------- knorm: normalize linrP planes -> xrI interleaved bf16 [e][k] ----------------
__global__ __launch_bounds__(256) void knorm(const __hip_bfloat16* __restrict__ linrP,
                                             const float* __restrict__ norm_a,
                                             __hip_bfloat16* __restrict__ xrI){
  const size_t base = ((size_t)blockIdx.x*256 + threadIdx.x) * 8;   // 8 e's per thread
  const short* lp = (const short*)linrP;
  short8 v[8];
  #pragma unroll
  for(int i=0;i<8;i++) v[i] = *(const short8*)(lp + (size_t)i*2097152 + base);
  short8 o[8];
  #pragma unroll
  for(int s=0;s<8;s++){
    float u[8];
    #pragma unroll
    for(int i=0;i<8;i++) u[i] = bf2f(v[i][s]);
    int n = (int)((base + s) & 511);
    float4 na = *(const float4*)(norm_a + n*4);
    norm8v(u, na);
    #pragma unroll
    for(int i=0;i<8;i++) o[s][i] = f2bf(u[i]);
  }
  short* op = (short*)xrI;
  #pragma unroll
  for(int s=0;s<8;s++) *(short8*)(op + (base+s)*8) = o[s];
}

// ---------------- k2_mfma: fcgp1 product via per-j register-built A fragments ----------------
// Bpack layout: [sp][nc][j][q][m][i] — 16KB contiguous per (sp,nc).
__global__ __launch_bounds__(256) void k2_mfma(const float* __restrict__ x,
                                               const __hip_bfloat16* __restrict__ xrI,
                                               const __hip_bfloat16* __restrict__ Bpack,
                                               float* __restrict__ h1part){
  const int tid = threadIdx.x;
  const int l = tid & 63, w = tid >> 6;
  const int row = blockIdx.x*64 + w*16 + (l & 15);
  const int nsb = blockIdx.y * 64;
  const int boff = (l>>4)*256 + (l&15)*8;
  floatx4 acc[8][2] = {};

  for(int nc = 0; nc < 16; nc++){
    const int n = nsb + nc*4 + (l>>4);
    const size_t e = (size_t)row*512 + n;
    float4 xa = *(const float4*)(x + e*8);
    float4 xb = *(const float4*)(x + e*8 + 4);
    float xv[8] = {xa.x,xa.y,xa.z,xa.w,xb.x,xb.y,xb.z,xb.w};
    short8 xri = *(const short8*)((const short*)xrI + e*8);
    float xr[8];
    #pragma unroll
    for(int i=0;i<8;i++) xr[i] = bf2f(xri[i]);
    const __hip_bfloat16* bp_nc = Bpack + (size_t)(blockIdx.y*16 + nc)*8192 + boff;
    #pragma unroll
    for(int j=0;j<8;j++){
      short8 af;
      #pragma unroll
      for(int i=0;i<8;i++) af[i] = f2bf(xv[i] * xr[c_kof(j,i)]);
      short8 b0 = *(const short8*)(bp_nc + j*1024);
      short8 b1 = *(const short8*)(bp_nc + j*1024 + 128);
      acc[j][0] = __builtin_amdgcn_mfma_f32_16x16x32_bf16(af, b0, acc[j][0], 0, 0, 0);
      acc[j][1] = __builtin_amdgcn_mfma_f32_16x16x32_bf16(af, b1, acc[j][1], 0, 0, 0);
    }
  }
  const int sp = blockIdx.y;
  #pragma unroll
  for(int j=0;j<8;j++){
    #pragma unroll
    for(int mf=0; mf<2; mf++){
      #pragma unroll
      for(int r=0; r<4; r++){
        int b = blockIdx.x*64 + w*16 + (l>>4)*4 + r;
        h1part[((size_t)(sp*8+j))*131072 + b*32 + mf*16 + (l&15)] = acc[j][mf][r];
      }
    }
  }
}

// ---------------- K2b: reduce + left + bias + silu -> h1s f32 + h1P bf16 planes ----------------
__global__ __launch_bounds__(256) void k2b_silu(const float* __restrict__ h1part,
                                                const float* __restrict__ leftB,
                                                const float* __restrict__ bl,
                                                const float* __restrict__ sa,
                                                const float* __restrict__ sb,
                                                float* __restrict__ h1s,
                                                __hip_bfloat16* __restrict__ h1P){
  int idx = blockIdx.x*256 + threadIdx.x;  // b*32+m
  int m = idx & 31;
  float v[8];
  #pragma unroll
  for(int j=0;j<8;j++){
    float s = leftB[(size_t)j*131072 + idx];
    #pragma unroll
    for(int sp=0; sp<8; sp++) s += h1part[((size_t)(sp*8+j))*131072 + idx];
    v[j] = s;
  }
  v[0] += bl[m];
  #pragma unroll
  for(int i=0;i<8;i++) v[i] *= INV_SQRT2F;
  float q1 = v[1]*v[1]+v[2]*v[2]+v[3]*v[3];
  float q2 = v[4]*v[4]+v[5]*v[5]+v[6]*v[6];
  float q3 = v[7]*v[7];
  float4 sa4 = *(const float4*)&sa[m*4];
  float4 sb4 = *(const float4*)&sb[m*4];
  float g0 = sigf(sa4.x*v[0] + sb4.x);
  float g1 = sigf(sa4.y*q1   + sb4.y);
  float g2 = sigf(sa4.z*q2   + sb4.z);
  float g3 = sigf(sa4.w*q3   + sb4.w);
  float o[8] = {g0*v[0], g1*v[1], g1*v[2], g1*v[3], g2*v[4], g2*v[5], g2*v[6], g3*v[7]};
  *(float4*)&h1s[(size_t)idx*8]     = make_float4(o[0],o[1],o[2],o[3]);
  *(float4*)&h1s[(size_t)idx*8 + 4] = make_float4(o[4],o[5],o[6],o[7]);
  #pragma unroll
  for(int j=0;j<8;j++) h1P[(size_t)j*131072 + idx] = __float2bfloat16(o[j]);
}

// ---------------- k3a: linr2/left2 [j][b][n] = sum_m h1P[j][b][m] * w2{r,l}P[j][n][m] ----------------
__global__ __launch_bounds__(256) void k3a(const __hip_bfloat16* __restrict__ h1P,
                                           const __hip_bfloat16* __restrict__ w2rP,
                                           const __hip_bfloat16* __restrict__ w2lP,
                                           float* __restrict__ linr2,
                                           float* __restrict__ left2){
  const int tid = threadIdx.x;
  const int l = tid & 63, w = tid >> 6;
  const int j = blockIdx.y;
  const int row = blockIdx.x*64 + w*16 + (l & 15);
  const int ko = (l>>4)*8;
  short8 a   = *(const short8*)(h1P + (size_t)j*131072 + (size_t)row*32 + ko);
  short8 br0 = *(const short8*)(w2rP + j*1024 + (l&15)*32 + ko);
  short8 br1 = *(const short8*)(w2rP + j*1024 + ((l&15)+16)*32 + ko);
  short8 bl0 = *(const short8*)(w2lP + j*1024 + (l&15)*32 + ko);
  short8 bl1 = *(const short8*)(w2lP + j*1024 + ((l&15)+16)*32 + ko);
  floatx4 aR0 = {}, aR1 = {}, aL0 = {}, aL1 = {};
  aR0 = __builtin_amdgcn_mfma_f32_16x16x32_bf16(a, br0, aR0, 0, 0, 0);
  aR1 = __builtin_amdgcn_mfma_f32_16x16x32_bf16(a, br1, aR1, 0, 0, 0);
  aL0 = __builtin_amdgcn_mfma_f32_16x16x32_bf16(a, bl0, aL0, 0, 0, 0);
  aL1 = __builtin_amdgcn_mfma_f32_16x16x32_bf16(a, bl1, aL1, 0, 0, 0);
  #pragma unroll
  for(int r=0; r<4; r++){
    int b = blockIdx.x*64 + w*16 + (l>>4)*4 + r;
    linr2[(size_t)j*131072 + b*32 + (l&15)]      = aR0[r];
    linr2[(size_t)j*131072 + b*32 + 16 + (l&15)] = aR1[r];
    left2[(size_t)j*131072 + b*32 + (l&15)]      = aL0[r];
    left2[(size_t)j*131072 + b*32 + 16 + (l&15)] = aL1[r];
  }
}

// ---------------- k3b: norm(linr2) -> x2; sgp + left2 + bias + silu -> h2f, h2P ----------------
__global__ __launch_bounds__(256) void k3b(const float* __restrict__ linr2,
                                           const float* __restrict__ left2,
                                           const float* __restrict__ h1s,
                                           const float* __restrict__ na2,
                                           const float* __restrict__ gw2,
                                           const float* __restrict__ b2l,
                                           const float* __restrict__ sa,
                                           const float* __restrict__ sb,
                                           float* __restrict__ h2f,
                                           __hip_bfloat16* __restrict__ h2P){
  int idx = blockIdx.x*256 + threadIdx.x;  // b*32+n
  int n = idx & 31;
  float x2[8];
  #pragma unroll
  for(int j=0;j<8;j++) x2[j] = linr2[(size_t)j*131072 + idx];
  norm8v(x2, *(const float4*)&na2[n*4]);
  float4 h0 = *(const float4*)&h1s[(size_t)idx*8];
  float4 h1 = *(const float4*)&h1s[(size_t)idx*8 + 4];
  float h[8] = {h0.x,h0.y,h0.z,h0.w,h1.x,h1.y,h1.z,h1.w};
  const float* g2 = gw2 + (size_t)n*64;
  float v[8];
  #pragma unroll
  for(int j=0;j<8;j++){
    float pr = 0.f;
    #pragma unroll
    for(int i=0;i<8;i++)
      pr = fmaf(c_cs(j,i) * h[i] * x2[c_kof(j,i)], g2[c_widx(j,i)], pr);
    v[j] = (pr + left2[(size_t)j*131072 + idx] + ((j==0) ? b2l[n] : 0.f)) * INV_SQRT2F;
  }
  float q1 = v[1]*v[1]+v[2]*v[2]+v[3]*v[3];
  float q2 = v[4]*v[4]+v[5]*v[5]+v[6]*v[6];
  float q3 = v[7]*v[7];
  float4 sa4 = *(const float4*)&sa[n*4];
  float4 sb4 = *(const float4*)&sb[n*4];
  float g0 = sigf(sa4.x*v[0] + sb4.x);
  float g1 = sigf(sa4.y*q1   + sb4.y);
  float gg2 = sigf(sa4.z*q2  + sb4.z);
  float g3 = sigf(sa4.w*q3   + sb4.w);
  float o[8] = {g0*v[0], g1*v[1], g1*v[2], g1*v[3], gg2*v[4], gg2*v[5], gg2*v[6], g3*v[7]};
  *(float4*)&h2f[(size_t)idx*8]     = make_float4(o[0],o[1],o[2],o[3]);
  *(float4*)&h2f[(size_t)idx*8 + 4] = make_float4(o[4],o[5],o[6],o[7]);
  #pragma unroll
  for(int j=0;j<8;j++) h2P[(size_t)j*131072 + idx] = __float2bfloat16(o[j]);
}

// ---------------- k3c: linr3[j][b][n] = sum_m h2P[j][b][m] * w3rP[j][n][m] ----------------
__global__ __launch_bounds__(256) void k3c(const __hip_bfloat16* __restrict__ h2P,
                                           const __hip_bfloat16* __restrict__ w3rP,
                                           float* __restrict__ linr3){
  const int tid = threadIdx.x;
  const int l = tid & 63, w = tid >> 6;
  const int j = blockIdx.y;
  const int row = blockIdx.x*64 + w*16 + (l & 15);
  const int ko = (l>>4)*8;
  short8 a   = *(const short8*)(h2P + (size_t)j*131072 + (size_t)row*32 + ko);
  short8 b0  = *(const short8*)(w3rP + j*1024 + (l&15)*32 + ko);
  short8 b1  = *(const short8*)(w3rP + j*1024 + ((l&15)+16)*32 + ko);
  floatx4 a0 = {}, a1 = {};
  a0 = __builtin_amdgcn_mfma_f32_16x16x32_bf16(a, b0, a0, 0, 0, 0);
  a1 = __builtin_amdgcn_mfma_f32_16x16x32_bf16(a, b1, a1, 0, 0, 0);
  #pragma unroll
  for(int r=0; r<4; r++){
    int b = blockIdx.x*64 + w*16 + (l>>4)*4 + r;
    linr3[(size_t)j*131072 + b*32 + (l&15)]      = a0[r];
    linr3[(size_t)j*131072 + b*32 + 16 + (l&15)] = a1[r];
  }
}

// ---------------- k3d: norm(linr3) -> x3; pairP[j][b][n*8+i] = bf16(h2[i]*x3[kof(j,i)]) ----------------
__global__ __launch_bounds__(256) void k3d(const float* __restrict__ linr3,
                                           const float* __restrict__ h2f,
                                           const float* __restrict__ na3,
                                           __hip_bfloat16* __restrict__ pairP){
  int idx = blockIdx.x*256 + threadIdx.x;  // b*32+n
  int n = idx & 31;
  float x3[8];
  #pragma unroll
  for(int j=0;j<8;j++) x3[j] = linr3[(size_t)j*131072 + idx];
  norm8v(x3, *(const float4*)&na3[n*4]);
  float4 h0 = *(const float4*)&h2f[(size_t)idx*8];
  float4 h1 = *(const float4*)&h2f[(size_t)idx*8 + 4];
  float h[8] = {h0.x,h0.y,h0.z,h0.w,h1.x,h1.y,h1.z,h1.w};
  #pragma unroll
  for(int j=0;j<8;j++){
    short8 o;
    #pragma unroll
    for(int i=0;i<8;i++) o[i] = f2bf(h[i] * x3[c_kof(j,i)]);
    *(short8*)(pairP + (size_t)j*1048576 + (size_t)idx*8) = o;
  }
}

// ---------------- k3e: out[b][mo][j] = (sum_k pair/h2 x Bp3 + bias) * c ----------------
__global__ __launch_bounds__(256) void k3e(const __hip_bfloat16* __restrict__ pairP,
                                           const __hip_bfloat16* __restrict__ h2P,
                                           const __hip_bfloat16* __restrict__ Bp3,
                                           const float* __restrict__ b3l,
                                           float* __restrict__ out){
  const int tid = threadIdx.x;
  const int l = tid & 63, w = tid >> 6;
  const int j = blockIdx.y;
  const int row = blockIdx.x*64 + w*16 + (l & 15);
  const int mo = l & 15;
  const int ko = (l>>4)*8;
  floatx4 acc = {};
  const __hip_bfloat16* Ap = pairP + (size_t)j*1048576 + (size_t)row*256;
  const __hip_bfloat16* Bp = Bp3 + (size_t)j*4608 + mo*288;
  #pragma unroll
  for(int kc=0; kc<8; kc++){
    short8 a = *(const short8*)(Ap + kc*32 + ko);
    short8 b = *(const short8*)(Bp + kc*32 + ko);
    acc = __builtin_amdgcn_mfma_f32_16x16x32_bf16(a, b, acc, 0, 0, 0);
  }
  {
    short8 a = *(const short8*)(h2P + (size_t)j*131072 + (size_t)row*32 + ko);
    short8 b = *(const short8*)(Bp + 256 + ko);
    acc = __builtin_amdgcn_mfma_f32_16x16x32_bf16(a, b, acc, 0, 0, 0);
  }
  if(mo < 9){
    #pragma unroll
    for(int r=0; r<4; r++){
      int b = blockIdx.x*64 + w*16 + (l>>4)*4 + r;
      out[((size_t)b*9 + mo)*8 + j] = (acc[r] + ((j==0) ? b3l[mo] : 0.f)) * INV_SQRT2F;
    }
  }
}

// ---------------- launch ----------------
extern "C" void kernel_launch(void* const* d_in, const int* in_sizes, int n_in,
                              void* d_out, int out_size, void* d_ws, size_t ws_size,
                              hipStream_t stream){
  const float* x        = (const float*)d_in[0];
  const float* w_right1 = (const float*)d_in[1];
  const float* norm_a1  = (const float*)d_in[2];
  const float* w_left1  = (const float*)d_in[3];
  const float* b_left1  = (const float*)d_in[4];
  const float* gp_w1    = (const float*)d_in[5];
  const float* silu_a   = (const float*)d_in[6];
  const float* silu_b   = (const float*)d_in[7];
  const float* w_right2 = (const float*)d_in[8];
  const float* norm_a2  = (const float*)d_in[9];
  const float* w_left2  = (const float*)d_in[10];
  const float* b_left2  = (const float*)d_in[11];
  const float* gp_w2    = (const float*)d_in[12];
  const float* w_right3 = (const float*)d_in[13];
  const float* norm_a3  = (const float*)d_in[14];
  const float* w_left3  = (const float*)d_in[15];
  const float* b_left3  = (const float*)d_in[16];
  const float* gp_w3    = (const float*)d_in[17];
  float* out = (float*)d_out;

  char* wsb = (char*)d_ws;
  // ws layout (peak ~82.2 MB):
  //  [0,32M):   xP (pack_x..k_left) -> xrI (knorm..k2) -> pairP(16M)@0 + tail:
  //             linr2 @16,777,216  left2 @20,971,520  h2f @25,165,824  h2P @29,360,128
  //  [32M,34M): wP (dead after k1) -> h1P bf16 [8][131072]
  //  [35,651,584, 39,845,888): h1s f32
  //  [41,943,040, 75,497,472): linrP (dead after knorm) -> h1part f32 [64][131072]
  //             -> linr3 @41,943,040 (after k2b)
  //  [75,497,472,...): Bpack(2M), wlP(0.25M), leftB(4M), small tail packs
  __hip_bfloat16* xP    = (__hip_bfloat16*)wsb;
  __hip_bfloat16* xrI   = (__hip_bfloat16*)wsb;
  __hip_bfloat16* pairP = (__hip_bfloat16*)wsb;
  float*          linr2 = (float*)(wsb + 16777216);
  float*          left2 = (float*)(wsb + 20971520);
  float*          h2f   = (float*)(wsb + 25165824);
  __hip_bfloat16* h2P   = (__hip_bfloat16*)(wsb + 29360128);
  __hip_bfloat16* wP    = (__hip_bfloat16*)(wsb + 33554432);
  __hip_bfloat16* h1P   = (__hip_bfloat16*)(wsb + 33554432);
  float*          h1s   = (float*)(wsb + 35651584);
  __hip_bfloat16* linrP = (__hip_bfloat16*)(wsb + 41943040);
  float*          h1part= (float*)(wsb + 41943040);
  float*          linr3 = (float*)(wsb + 41943040);
  __hip_bfloat16* Bpack = (__hip_bfloat16*)(wsb + 75497472);
  __hip_bfloat16* wlP   = (__hip_bfloat16*)(wsb + 77594624);
  float*          leftB = (float*)(wsb + 77856768);
  __hip_bfloat16* w2rP  = (__hip_bfloat16*)(wsb + 82051072);
  __hip_bfloat16* w2lP  = (__hip_bfloat16*)(wsb + 82051072 + 16384);
  __hip_bfloat16* w3rP  = (__hip_bfloat16*)(wsb + 82051072 + 32768);
  __hip_bfloat16* Bp3   = (__hip_bfloat16*)(wsb + 82051072 + 49152);

  pack_x<<<8192, 256, 0, stream>>>(x, xP);
  pack_misc<<<2288, 256, 0, stream>>>(w_right1, gp_w1, w_left1,
                                      w_right2, w_left2, w_right3, gp_w3, w_left3,
                                      wP, Bpack, wlP, w2rP, w2lP, w3rP, Bp3);
  k1_mfma<<<dim3(32, 4, 8), 256, 0, stream>>>(xP, wP, linrP);
  k_left<<<dim3(64, 8), 256, 0, stream>>>(xP, wlP, leftB);
  knorm<<<1024, 256, 0, stream>>>(linrP, norm_a1, xrI);
  k2_mfma<<<dim3(64, 8), 256, 0, stream>>>(x, xrI, Bpack, h1part);
  k2b_silu<<<512, 256, 0, stream>>>(h1part, leftB, b_left1, silu_a, silu_b, h1s, h1P);
  k3a<<<dim3(64, 8), 256, 0, stream>>>(h1P, w2rP, w2lP, linr2, left2);
  k3b<<<512, 256, 0, stream>>>(linr2, left2, h1s, norm_a2, gp_w2, b_left2,
                               silu_a, silu_b, h2f, h2P);
  k3c<<<dim3(64, 8), 256, 0, stream>>>(h2P, w3rP, linr3);
  k3d<<<512, 256, 0, stream>>>(linr3, h2f, norm_a3, pairP);
  k3e<<<dim3(64, 8), 256, 0, stream>>>(pairP, h2P, Bp3, b_left3, out);
}